// Round 5
// baseline (2000.782 us; speedup 1.0000x reference)
//
#include <hip/hip_runtime.h>

typedef __attribute__((ext_vector_type(8))) __bf16 b16x8;
typedef __attribute__((ext_vector_type(4))) float f32x4;
typedef __attribute__((ext_vector_type(8))) unsigned short u16x8;
typedef unsigned short u16;
typedef unsigned int u32;

#define MFMA16(a, b, c) __builtin_amdgcn_mfma_f32_16x16x32_bf16((a), (b), (c), 0, 0, 0)
// XOR swizzle: spread 16B slots across banks for row-major bf16 tiles w/ 256B row stride
#define SW(byteoff, row) ((byteoff) ^ (((row) & 7) << 4))
#define LOG2E 1.4426950408889634f

__device__ __forceinline__ u16 f2bf_bits(float f) {
  union { float f; unsigned u; } v; v.f = f;
  unsigned r = (v.u + 0x7FFFu + ((v.u >> 16) & 1u)) >> 16;
  return (u16)r;
}
__device__ __forceinline__ float rcp_f(float x) { float r; asm("v_rcp_f32 %0, %1" : "=v"(r) : "v"(x)); return r; }
__device__ __forceinline__ float exp2_f(float x) { float r; asm("v_exp_f32 %0, %1" : "=v"(r) : "v"(x)); return r; }
__device__ __forceinline__ f32x4 fzero4() { f32x4 z; z[0]=0.f; z[1]=0.f; z[2]=0.f; z[3]=0.f; return z; }
__device__ __forceinline__ b16x8 bzero8() {
  b16x8 z;
  #pragma unroll
  for (int j = 0; j < 8; ++j) z[j] = (__bf16)0.f;
  return z;
}
// barrier that drains only LDS (no vmcnt drain): loads/stores fly across
__device__ __forceinline__ void bar_lgkm() {
  asm volatile("s_waitcnt lgkmcnt(0)\n\ts_barrier" ::: "memory");
}

// ---------------- prep: weights -> bf16 (gate weights pre-scaled by log2e) ----------------
__global__ __launch_bounds__(256) void prep_kernel(
    const float* __restrict__ W1, const float* __restrict__ W2,
    const float* __restrict__ Wih, const float* __restrict__ Whh,
    const float* __restrict__ Wp, const float* __restrict__ Wv,
    const float* __restrict__ bih, const float* __restrict__ bhh,
    u16* __restrict__ W1b, u16* __restrict__ W2b, u16* __restrict__ Wihb,
    u16* __restrict__ Whhb, u16* __restrict__ Whb, float* __restrict__ gbp)
{
  int i = blockIdx.x * 256 + threadIdx.x;   // grid 256*256 = 65536
  if (i < 8192) {                            // W1 padded (128 x 64), K 54->64
    int r = i >> 6, k = i & 63;
    W1b[i] = f2bf_bits(k < 54 ? W1[r * 54 + k] : 0.f);
  }
  if (i < 16384) W2b[i] = f2bf_bits(W2[i]);  // 128x128
  Wihb[i] = f2bf_bits(LOG2E * Wih[i]);       // 512x128, pre-scaled
  Whhb[i] = f2bf_bits(LOG2E * Whh[i]);       // 512x128, pre-scaled
  if (i < 2048) {                            // head: rows 0-5 Wp, 6 Wv, 7-15 zero (16x128)
    int r = i >> 7, k = i & 127;
    float v = (r < 6) ? Wp[r * 128 + k] : ((r == 6) ? Wv[k] : 0.f);
    Whb[i] = f2bf_bits(v);                   // NOT scaled
  }
  if (i < 512) gbp[i] = LOG2E * (bih[i] + bhh[i]);
}

// ---------------- phase 1: X2 = relu(relu(obs@W1^T+b1)@W2^T+b2) as bf16 ----------------
__global__ __launch_bounds__(256) void mlp_kernel(
    const float* __restrict__ obs, const float* __restrict__ b1v, const float* __restrict__ b2v,
    const u16* __restrict__ W1b, const u16* __restrict__ W2b, u16* __restrict__ X2)
{
  __shared__ __align__(16) float obst[64 * 54];
  __shared__ u16 x1t[64 * 128];
  __shared__ u16 x2t[64 * 128];
  const int tid = threadIdx.x;
  const int w   = tid >> 6;
  const int l   = tid & 63;
  const int col = l & 15;
  const int q   = l >> 4;
  const long m0 = (long)blockIdx.x * 64;   // 4096 blocks * 64 rows = 262144 = T*N

  {
    const float* osrc = obs + m0 * 54;
    #pragma unroll
    for (int j = 0; j < 4; ++j) {
      int i4 = tid + 256 * j;
      if (i4 < 864) *(float4*)&obst[i4 * 4] = *(const float4*)&osrc[i4 * 4];
    }
  }
  __syncthreads();

  b16x8 a0[2];
  {
    const float* orow = obst + (16 * w + col) * 54;
    #pragma unroll
    for (int c = 0; c < 2; ++c) {
      #pragma unroll
      for (int p = 0; p < 4; ++p) {
        int k0 = 32 * c + 8 * q + 2 * p;
        float x0 = 0.f, x1 = 0.f;
        if (k0 < 54) { x0 = orow[k0]; x1 = orow[k0 + 1]; }
        a0[c][2 * p]     = (__bf16)x0;
        a0[c][2 * p + 1] = (__bf16)x1;
      }
    }
  }
  f32x4 acc[8];
  #pragma unroll
  for (int i = 0; i < 8; ++i) acc[i] = fzero4();
  #pragma unroll
  for (int nt = 0; nt < 8; ++nt) {
    #pragma unroll
    for (int c = 0; c < 2; ++c) {
      b16x8 b = *(const b16x8*)(W1b + (nt * 16 + col) * 64 + 8 * q + 32 * c);
      acc[nt] = MFMA16(a0[c], b, acc[nt]);
    }
  }
  #pragma unroll
  for (int nt = 0; nt < 8; ++nt) {
    float bb = b1v[nt * 16 + col];
    #pragma unroll
    for (int r = 0; r < 4; ++r) {
      float v = fmaxf(acc[nt][r] + bb, 0.f);
      int row = 16 * w + 4 * q + r;
      int byteoff = row * 256 + (nt * 16 + col) * 2;
      *(u16*)((char*)x1t + SW(byteoff, row)) = f2bf_bits(v);
    }
  }
  __syncthreads();

  b16x8 a1[4];
  #pragma unroll
  for (int c = 0; c < 4; ++c) {
    int row = 16 * w + col;
    int byteoff = row * 256 + 16 * q + 64 * c;
    a1[c] = *(const b16x8*)((char*)x1t + SW(byteoff, row));
  }
  f32x4 acc2[8];
  #pragma unroll
  for (int i = 0; i < 8; ++i) acc2[i] = fzero4();
  #pragma unroll
  for (int nt = 0; nt < 8; ++nt) {
    #pragma unroll
    for (int c = 0; c < 4; ++c) {
      b16x8 b = *(const b16x8*)(W2b + (nt * 16 + col) * 128 + 8 * q + 32 * c);
      acc2[nt] = MFMA16(a1[c], b, acc2[nt]);
    }
  }
  #pragma unroll
  for (int nt = 0; nt < 8; ++nt) {
    float bb = b2v[nt * 16 + col];
    #pragma unroll
    for (int r = 0; r < 4; ++r) {
      float v = fmaxf(acc2[nt][r] + bb, 0.f);
      int row = 16 * w + 4 * q + r;
      int byteoff = row * 256 + (nt * 16 + col) * 2;
      *(u16*)((char*)x2t + SW(byteoff, row)) = f2bf_bits(v);
    }
  }
  __syncthreads();

  #pragma unroll
  for (int i = 0; i < 4; ++i) {
    int e = tid + 256 * i;
    int byteoff = e * 16;
    int row = byteoff >> 8;
    uint4 v = *(const uint4*)((char*)x2t + SW(byteoff, row));
    *(uint4*)((char*)X2 + m0 * 256 + byteoff) = v;
  }
}

// ---------------- phase 2: LSTM recurrence + fused 2-step heads ----------------
// 512 blocks x 4 batch rows, 512 threads (8 waves, 2 blocks/CU -> 4 waves/SIMD).
// M=16 tile rows 4-7 mirror rows 0-3 (bit-identical duplicate compute); mirror
// lanes' duplicate global stores write identical values (benign).
__global__ __launch_bounds__(512, 4) void lstm_kernel(
    const u16* __restrict__ X2, const float* __restrict__ h0, const float* __restrict__ c0,
    const int* __restrict__ done,
    const u16* __restrict__ Wihb, const u16* __restrict__ Whhb, const u16* __restrict__ Whb,
    const float* __restrict__ gb, const float* __restrict__ bp, const float* __restrict__ bv,
    float* __restrict__ out)
{
  __shared__ u16 hring[4][8 * 128];  // 4-deep ring of h tiles (swizzled; rows 4-7 mirror 0-3)
  __shared__ int dsh[1024];          // done[t][rows 0-7 (mirrored)] staged
  const int tid = threadIdx.x;
  const int w   = tid >> 6;
  const int l   = tid & 63;
  const int col = l & 15;
  const int q   = l >> 4;
  const int cl  = col & 7;           // LDS h row (mirror space)
  const int clx = col & 3;           // real batch row offset for X2
  const int n0  = blockIdx.x * 4;    // 512 blocks * 4 rows = 2048
  // elementwise-spread row base: q0->0, q1->4, q2->2, q3->6 (each lane owns rows rbase, rbase+1)
  const int rbase = ((q & 1) << 2) + ((q >> 1) << 1);

  // resident gate-weight fragments (pre-scaled by log2e)
  b16x8 wih[4][4], whh[4][4];
  #pragma unroll
  for (int g = 0; g < 4; ++g) {
    int nt = 8 * g + w;
    #pragma unroll
    for (int c = 0; c < 4; ++c) {
      wih[g][c] = *(const b16x8*)(Wihb + (nt * 16 + col) * 128 + 8 * q + 32 * c);
      whh[g][c] = *(const b16x8*)(Whhb + (nt * 16 + col) * 128 + 8 * q + 32 * c);
    }
  }
  float gbr[4];
  #pragma unroll
  for (int g = 0; g < 4; ++g) gbr[g] = gb[(8 * g + w) * 16 + col];
  const float hb = (col < 6) ? bp[col] : ((col == 6) ? bv[0] : 0.f);

  // c-state: 2 cells per lane (mirror rows rbase, rbase+1 -> batch rows &3)
  float cc0 = c0[(n0 + (rbase & 3)) * 128 + 16 * w + col];
  float cc1 = c0[(n0 + ((rbase + 1) & 3)) * 128 + 16 * w + col];

  // stage h0 -> hring[0] (rows 4-7 mirror 0-3); done -> dsh (mirrored)
  #pragma unroll
  for (int j = 0; j < 2; ++j) {
    int idx = tid * 2 + j;           // 1024 = 8 rows * 128
    int row = idx >> 7, k = idx & 127;
    *(u16*)((char*)hring[0] + SW(row * 256 + k * 2, row)) = f2bf_bits(h0[(n0 + (row & 3)) * 128 + k]);
    dsh[idx] = done[(idx >> 3) * 2048 + n0 + (idx & 3)];
  }
  __syncthreads();

  // loop-invariant LDS offsets
  int offr[4];
  #pragma unroll
  for (int c = 0; c < 4; ++c) offr[c] = SW(cl * 256 + 16 * q + 64 * c, cl);
  const int wcol2 = (16 * w + col) * 2;
  const int offw0 = SW(rbase * 256 + wcol2, rbase);
  const int offw1 = SW((rbase + 1) * 256 + wcol2, rbase + 1);

  // x2 fragment pointer (per-lane); t=0 preloaded, xp then points at t+1
  const u16* xp = X2 + (n0 + clx) * 128 + 8 * q;
  b16x8 xa[4];
  #pragma unroll
  for (int c = 0; c < 4; ++c) xa[c] = *(const b16x8*)(xp + 32 * c);
  xp += 262144;

  int dA = 0, dC0 = 0, dC1 = 0;
  float hv0 = 0.f, hv1 = 0.f;

  for (int tb = 0; tb < 128; tb += 4) {
    #pragma unroll
    for (int u = 0; u < 4; ++u) {
      const int t = tb + u;
      const u16* rbuf = hring[u];
      u16* wbuf = hring[(u + 1) & 3];

      // fused head for pair (t-2, t-1), rotated across waves (reads slots (u+3)&3 and u)
      if (((t & 1) == 0) && (t >= 2) && (w == (((t - 2) >> 1) & 7))) {
        const u16* bufA = hring[(u + 3) & 3];   // h_{t-2}
        const char* hbase = (const char*)((col < 8) ? bufA : rbuf);
        f32x4 hacc = fzero4();
        #pragma unroll
        for (int c = 0; c < 4; ++c) {
          b16x8 hh = *(const b16x8*)(hbase + offr[c]);
          b16x8 wf = *(const b16x8*)(Whb + col * 128 + 8 * q + 32 * c);
          hacc = MFMA16(hh, wf, hacc);
        }
        #pragma unroll
        for (int r = 0; r < 4; ++r) {
          int m = 4 * q + r;
          int tt = (t - 2) + (m >> 3);
          int n = n0 + (m & 3);              // mirror rows double-write same value
          float v = hacc[r] + hb;
          if (col < 6)       out[(tt * 2048 + n) * 6 + col] = v;
          else if (col == 6) out[1572864 + tt * 2048 + n] = v;
        }
      }

      // h_{t-1} fragments; zero rows where episode ended at t-1
      b16x8 ha[4];
      #pragma unroll
      for (int c = 0; c < 4; ++c) {
        ha[c] = *(const b16x8*)((const char*)rbuf + offr[c]);
        if (dA) ha[c] = bzero8();
      }
      if (dC0) cc0 = 0.f;
      if (dC1) cc1 = 0.f;

      // prefetch next step's x fragments (flies across barriers; no vmcnt drain)
      b16x8 xn[4];
      #pragma unroll
      for (int c = 0; c < 4; ++c) xn[c] = *(const b16x8*)(xp + 32 * c);

      f32x4 acc[4];
      #pragma unroll
      for (int g = 0; g < 4; ++g) acc[g] = fzero4();
      #pragma unroll
      for (int g = 0; g < 4; ++g)
        #pragma unroll
        for (int c = 0; c < 4; ++c)
          acc[g] = MFMA16(xa[c], wih[g][c], acc[g]);
      #pragma unroll
      for (int g = 0; g < 4; ++g)
        #pragma unroll
        for (int c = 0; c < 4; ++c)
          acc[g] = MFMA16(ha[c], whh[g][c], acc[g]);

      // masks for next step (done[t]), mirrored rows
      dA  = dsh[t * 8 + cl];
      dC0 = dsh[t * 8 + rbase];
      dC1 = dsh[t * 8 + rbase + 1];

      // spread cells across all lanes: q2/q3 take partner's acc rows 2,3
      #pragma unroll
      for (int g = 0; g < 4; ++g) {
        asm volatile("v_permlane32_swap_b32 %0, %1" : "+v"(acc[g][0]), "+v"(acc[g][2]));
        asm volatile("v_permlane32_swap_b32 %0, %1" : "+v"(acc[g][1]), "+v"(acc[g][3]));
      }

      // elementwise LSTM cell, 2 cells/lane (gates pre-scaled by log2e)
      {
        float gi = acc[0][0] + gbr[0], gf = acc[1][0] + gbr[1];
        float gg = acc[2][0] + gbr[2], go = acc[3][0] + gbr[3];
        float si = rcp_f(1.f + exp2_f(-gi));
        float sf = rcp_f(1.f + exp2_f(-gf));
        float tg = 1.f - 2.f * rcp_f(1.f + exp2_f(gg + gg));
        float cn = sf * cc0 + si * tg;
        float so = rcp_f(1.f + exp2_f(-go));
        float tc = 1.f - 2.f * rcp_f(1.f + exp2_f(2.8853900817779268f * cn));
        cc0 = cn; hv0 = so * tc;
      }
      {
        float gi = acc[0][1] + gbr[0], gf = acc[1][1] + gbr[1];
        float gg = acc[2][1] + gbr[2], go = acc[3][1] + gbr[3];
        float si = rcp_f(1.f + exp2_f(-gi));
        float sf = rcp_f(1.f + exp2_f(-gf));
        float tg = 1.f - 2.f * rcp_f(1.f + exp2_f(gg + gg));
        float cn = sf * cc1 + si * tg;
        float so = rcp_f(1.f + exp2_f(-go));
        float tc = 1.f - 2.f * rcp_f(1.f + exp2_f(2.8853900817779268f * cn));
        cc1 = cn; hv1 = so * tc;
      }

      // pack h -> bf16, write to ring slot (u+1)&3 (mirror lanes write mirror rows)
      {
        u32 pk;
        asm("v_cvt_pk_bf16_f32 %0, %1, %2" : "=v"(pk) : "v"(hv0), "v"(hv1));
        *(u16*)((char*)wbuf + offw0) = (u16)pk;
        *(u16*)((char*)wbuf + offw1) = (u16)(pk >> 16);
      }
      bar_lgkm();   // LDS-only drain; global loads/stores stay in flight

      #pragma unroll
      for (int c = 0; c < 4; ++c) xa[c] = xn[c];
      xp += 262144;
    }
  }

  // final head pair (126,127): h126 in slot 3, h127 in slot 0
  if (w == 7) {
    const char* hbase = (const char*)((col < 8) ? hring[3] : hring[0]);
    f32x4 hacc = fzero4();
    #pragma unroll
    for (int c = 0; c < 4; ++c) {
      b16x8 hh = *(const b16x8*)(hbase + offr[c]);
      b16x8 wf = *(const b16x8*)(Whb + col * 128 + 8 * q + 32 * c);
      hacc = MFMA16(hh, wf, hacc);
    }
    #pragma unroll
    for (int r = 0; r < 4; ++r) {
      int m = 4 * q + r;
      int tt = 126 + (m >> 3);
      int n = n0 + (m & 3);
      float v = hacc[r] + hb;
      if (col < 6)       out[(tt * 2048 + n) * 6 + col] = v;
      else if (col == 6) out[1572864 + tt * 2048 + n] = v;
    }
  }

  // final hT / cT (f32), 2 rows per lane — only non-mirror lanes (rbase 0,2)
  if (!(rbase & 4)) {
    int k = 16 * w + col;
    out[1835008 + (n0 + rbase) * 128 + k]     = hv0;
    out[1835008 + (n0 + rbase + 1) * 128 + k] = hv1;
    out[2097152 + (n0 + rbase) * 128 + k]     = cc0;
    out[2097152 + (n0 + rbase + 1) * 128 + k] = cc1;
  }
}

extern "C" void kernel_launch(void* const* d_in, const int* in_sizes, int n_in,
                              void* d_out, int out_size, void* d_ws, size_t ws_size,
                              hipStream_t stream) {
  const float* obs  = (const float*)d_in[0];
  const float* h0   = (const float*)d_in[1];
  const float* c0   = (const float*)d_in[2];
  const int*   done = (const int*)d_in[3];
  const float* W1   = (const float*)d_in[4];
  const float* b1   = (const float*)d_in[5];
  const float* W2   = (const float*)d_in[6];
  const float* b2   = (const float*)d_in[7];
  const float* Wih  = (const float*)d_in[8];
  const float* Whh  = (const float*)d_in[9];
  const float* bih  = (const float*)d_in[10];
  const float* bhh  = (const float*)d_in[11];
  const float* Wp   = (const float*)d_in[12];
  const float* bp   = (const float*)d_in[13];
  const float* Wv   = (const float*)d_in[14];
  const float* bv   = (const float*)d_in[15];

  char* ws = (char*)d_ws;
  u16*   X2   = (u16*)(ws);                                      // 67108864 B
  u16*   W1b  = (u16*)(ws + 67108864);                           // 16384 B
  u16*   W2b  = (u16*)(ws + 67108864 + 16384);                   // 32768 B
  u16*   Wihb = (u16*)(ws + 67108864 + 16384 + 32768);           // 131072 B
  u16*   Whhb = (u16*)(ws + 67108864 + 16384 + 32768 + 131072);  // 131072 B
  u16*   Whb  = (u16*)(ws + 67108864 + 16384 + 32768 + 262144);  // 4096 B
  float* gbp  = (float*)(ws + 67108864 + 16384 + 32768 + 262144 + 4096);
  float* out  = (float*)d_out;

  hipLaunchKernelGGL(prep_kernel, dim3(256), dim3(256), 0, stream,
                     W1, W2, Wih, Whh, Wp, Wv, bih, bhh, W1b, W2b, Wihb, Whhb, Whb, gbp);
  hipLaunchKernelGGL(mlp_kernel, dim3(4096), dim3(256), 0, stream,
                     obs, b1, b2, W1b, W2b, X2);
  hipLaunchKernelGGL(lstm_kernel, dim3(512), dim3(512), 0, stream,
                     X2, h0, c0, done, Wihb, Whhb, Whb, gbp, bp, bv, out);
}

// Round 6
// 478.553 us; speedup vs baseline: 4.1809x; 4.1809x over previous
//
#include <hip/hip_runtime.h>

typedef __attribute__((ext_vector_type(8))) __bf16 b16x8;
typedef __attribute__((ext_vector_type(4))) float f32x4;
typedef __attribute__((ext_vector_type(8))) unsigned short u16x8;
typedef unsigned short u16;
typedef unsigned int u32;

#define MFMA16(a, b, c) __builtin_amdgcn_mfma_f32_16x16x32_bf16((a), (b), (c), 0, 0, 0)
// XOR swizzle: spread 16B slots across banks for row-major bf16 tiles w/ 256B row stride
#define SW(byteoff, row) ((byteoff) ^ (((row) & 7) << 4))
#define LOG2E 1.4426950408889634f

__device__ __forceinline__ u16 f2bf_bits(float f) {
  union { float f; unsigned u; } v; v.f = f;
  unsigned r = (v.u + 0x7FFFu + ((v.u >> 16) & 1u)) >> 16;
  return (u16)r;
}
__device__ __forceinline__ float rcp_f(float x) { float r; asm("v_rcp_f32 %0, %1" : "=v"(r) : "v"(x)); return r; }
__device__ __forceinline__ float exp2_f(float x) { float r; asm("v_exp_f32 %0, %1" : "=v"(r) : "v"(x)); return r; }
__device__ __forceinline__ f32x4 fzero4() { f32x4 z; z[0]=0.f; z[1]=0.f; z[2]=0.f; z[3]=0.f; return z; }
__device__ __forceinline__ b16x8 bzero8() {
  b16x8 z;
  #pragma unroll
  for (int j = 0; j < 8; ++j) z[j] = (__bf16)0.f;
  return z;
}
// barrier that drains only LDS (no vmcnt drain): loads/stores fly across
__device__ __forceinline__ void bar_lgkm() {
  asm volatile("s_waitcnt lgkmcnt(0)\n\ts_barrier" ::: "memory");
}

// ---------------- prep: weights -> bf16 (gate weights pre-scaled by log2e) ----------------
__global__ __launch_bounds__(256) void prep_kernel(
    const float* __restrict__ W1, const float* __restrict__ W2,
    const float* __restrict__ Wih, const float* __restrict__ Whh,
    const float* __restrict__ Wp, const float* __restrict__ Wv,
    const float* __restrict__ bih, const float* __restrict__ bhh,
    u16* __restrict__ W1b, u16* __restrict__ W2b, u16* __restrict__ Wihb,
    u16* __restrict__ Whhb, u16* __restrict__ Whb, float* __restrict__ gbp)
{
  int i = blockIdx.x * 256 + threadIdx.x;   // grid 256*256 = 65536
  if (i < 8192) {                            // W1 padded (128 x 64), K 54->64
    int r = i >> 6, k = i & 63;
    W1b[i] = f2bf_bits(k < 54 ? W1[r * 54 + k] : 0.f);
  }
  if (i < 16384) W2b[i] = f2bf_bits(W2[i]);  // 128x128
  Wihb[i] = f2bf_bits(LOG2E * Wih[i]);       // 512x128, pre-scaled
  Whhb[i] = f2bf_bits(LOG2E * Whh[i]);       // 512x128, pre-scaled
  if (i < 2048) {                            // head: rows 0-5 Wp, 6 Wv, 7-15 zero (16x128)
    int r = i >> 7, k = i & 127;
    float v = (r < 6) ? Wp[r * 128 + k] : ((r == 6) ? Wv[k] : 0.f);
    Whb[i] = f2bf_bits(v);                   // NOT scaled
  }
  if (i < 512) gbp[i] = LOG2E * (bih[i] + bhh[i]);
}

// ---------------- phase 1: X2 = relu(relu(obs@W1^T+b1)@W2^T+b2) as bf16 ----------------
__global__ __launch_bounds__(256) void mlp_kernel(
    const float* __restrict__ obs, const float* __restrict__ b1v, const float* __restrict__ b2v,
    const u16* __restrict__ W1b, const u16* __restrict__ W2b, u16* __restrict__ X2)
{
  __shared__ __align__(16) float obst[64 * 54];
  __shared__ u16 x1t[64 * 128];
  __shared__ u16 x2t[64 * 128];
  const int tid = threadIdx.x;
  const int w   = tid >> 6;
  const int l   = tid & 63;
  const int col = l & 15;
  const int q   = l >> 4;
  const long m0 = (long)blockIdx.x * 64;   // 4096 blocks * 64 rows = 262144 = T*N

  {
    const float* osrc = obs + m0 * 54;
    #pragma unroll
    for (int j = 0; j < 4; ++j) {
      int i4 = tid + 256 * j;
      if (i4 < 864) *(float4*)&obst[i4 * 4] = *(const float4*)&osrc[i4 * 4];
    }
  }
  __syncthreads();

  b16x8 a0[2];
  {
    const float* orow = obst + (16 * w + col) * 54;
    #pragma unroll
    for (int c = 0; c < 2; ++c) {
      #pragma unroll
      for (int p = 0; p < 4; ++p) {
        int k0 = 32 * c + 8 * q + 2 * p;
        float x0 = 0.f, x1 = 0.f;
        if (k0 < 54) { x0 = orow[k0]; x1 = orow[k0 + 1]; }
        a0[c][2 * p]     = (__bf16)x0;
        a0[c][2 * p + 1] = (__bf16)x1;
      }
    }
  }
  f32x4 acc[8];
  #pragma unroll
  for (int i = 0; i < 8; ++i) acc[i] = fzero4();
  #pragma unroll
  for (int nt = 0; nt < 8; ++nt) {
    #pragma unroll
    for (int c = 0; c < 2; ++c) {
      b16x8 b = *(const b16x8*)(W1b + (nt * 16 + col) * 64 + 8 * q + 32 * c);
      acc[nt] = MFMA16(a0[c], b, acc[nt]);
    }
  }
  #pragma unroll
  for (int nt = 0; nt < 8; ++nt) {
    float bb = b1v[nt * 16 + col];
    #pragma unroll
    for (int r = 0; r < 4; ++r) {
      float v = fmaxf(acc[nt][r] + bb, 0.f);
      int row = 16 * w + 4 * q + r;
      int byteoff = row * 256 + (nt * 16 + col) * 2;
      *(u16*)((char*)x1t + SW(byteoff, row)) = f2bf_bits(v);
    }
  }
  __syncthreads();

  b16x8 a1[4];
  #pragma unroll
  for (int c = 0; c < 4; ++c) {
    int row = 16 * w + col;
    int byteoff = row * 256 + 16 * q + 64 * c;
    a1[c] = *(const b16x8*)((char*)x1t + SW(byteoff, row));
  }
  f32x4 acc2[8];
  #pragma unroll
  for (int i = 0; i < 8; ++i) acc2[i] = fzero4();
  #pragma unroll
  for (int nt = 0; nt < 8; ++nt) {
    #pragma unroll
    for (int c = 0; c < 4; ++c) {
      b16x8 b = *(const b16x8*)(W2b + (nt * 16 + col) * 128 + 8 * q + 32 * c);
      acc2[nt] = MFMA16(a1[c], b, acc2[nt]);
    }
  }
  #pragma unroll
  for (int nt = 0; nt < 8; ++nt) {
    float bb = b2v[nt * 16 + col];
    #pragma unroll
    for (int r = 0; r < 4; ++r) {
      float v = fmaxf(acc2[nt][r] + bb, 0.f);
      int row = 16 * w + 4 * q + r;
      int byteoff = row * 256 + (nt * 16 + col) * 2;
      *(u16*)((char*)x2t + SW(byteoff, row)) = f2bf_bits(v);
    }
  }
  __syncthreads();

  #pragma unroll
  for (int i = 0; i < 4; ++i) {
    int e = tid + 256 * i;
    int byteoff = e * 16;
    int row = byteoff >> 8;
    uint4 v = *(const uint4*)((char*)x2t + SW(byteoff, row));
    *(uint4*)((char*)X2 + m0 * 256 + byteoff) = v;
  }
}

// ---------------- phase 2: LSTM recurrence + fused 2-step heads ----------------
// 512 blocks x 4 batch rows, 512 threads (8 waves). launch_bounds min-waves = 2
// (NOT 4: forcing 4 clamps VGPR to 64 and spills — round-5 regression). The
// natural allocation (~112 VGPR <= 128) lets HW co-schedule 2 blocks/CU ->
// 4 waves/SIMD. M=16 tile rows 4-7 mirror rows 0-3 (bit-identical duplicate
// compute); duplicate global stores write identical values (benign).
__global__ __launch_bounds__(512, 2) void lstm_kernel(
    const u16* __restrict__ X2, const float* __restrict__ h0, const float* __restrict__ c0,
    const int* __restrict__ done,
    const u16* __restrict__ Wihb, const u16* __restrict__ Whhb, const u16* __restrict__ Whb,
    const float* __restrict__ gb, const float* __restrict__ bp, const float* __restrict__ bv,
    float* __restrict__ out)
{
  __shared__ u16 hring[4][8 * 128];  // 4-deep ring of h tiles (swizzled; rows 4-7 mirror 0-3)
  __shared__ int dsh[1024];          // done[t][rows 0-7 (mirrored)] staged
  const int tid = threadIdx.x;
  const int w   = tid >> 6;
  const int l   = tid & 63;
  const int col = l & 15;
  const int q   = l >> 4;
  const int cl  = col & 7;           // LDS h row (mirror space)
  const int clx = col & 3;           // real batch row offset for X2
  const int n0  = blockIdx.x * 4;    // 512 blocks * 4 rows = 2048
  // elementwise-spread row base: q0->0, q1->4, q2->2, q3->6 (each lane owns rows rbase, rbase+1)
  const int rbase = ((q & 1) << 2) + ((q >> 1) << 1);

  // resident gate-weight fragments (pre-scaled by log2e)
  b16x8 wih[4][4], whh[4][4];
  #pragma unroll
  for (int g = 0; g < 4; ++g) {
    int nt = 8 * g + w;
    #pragma unroll
    for (int c = 0; c < 4; ++c) {
      wih[g][c] = *(const b16x8*)(Wihb + (nt * 16 + col) * 128 + 8 * q + 32 * c);
      whh[g][c] = *(const b16x8*)(Whhb + (nt * 16 + col) * 128 + 8 * q + 32 * c);
    }
  }
  float gbr[4];
  #pragma unroll
  for (int g = 0; g < 4; ++g) gbr[g] = gb[(8 * g + w) * 16 + col];
  const float hb = (col < 6) ? bp[col] : ((col == 6) ? bv[0] : 0.f);

  // c-state: 2 cells per lane (mirror rows rbase, rbase+1 -> batch rows &3)
  float cc0 = c0[(n0 + (rbase & 3)) * 128 + 16 * w + col];
  float cc1 = c0[(n0 + ((rbase + 1) & 3)) * 128 + 16 * w + col];

  // stage h0 -> hring[0] (rows 4-7 mirror 0-3); done -> dsh (mirrored)
  #pragma unroll
  for (int j = 0; j < 2; ++j) {
    int idx = tid * 2 + j;           // 1024 = 8 rows * 128
    int row = idx >> 7, k = idx & 127;
    *(u16*)((char*)hring[0] + SW(row * 256 + k * 2, row)) = f2bf_bits(h0[(n0 + (row & 3)) * 128 + k]);
    dsh[idx] = done[(idx >> 3) * 2048 + n0 + (idx & 3)];
  }
  __syncthreads();

  // loop-invariant LDS offsets
  int offr[4];
  #pragma unroll
  for (int c = 0; c < 4; ++c) offr[c] = SW(cl * 256 + 16 * q + 64 * c, cl);
  const int wcol2 = (16 * w + col) * 2;
  const int offw0 = SW(rbase * 256 + wcol2, rbase);
  const int offw1 = SW((rbase + 1) * 256 + wcol2, rbase + 1);

  // x2 fragment pointer (per-lane); t=0 preloaded, xp then points at t+1
  const u16* xp = X2 + (n0 + clx) * 128 + 8 * q;
  b16x8 xa[4];
  #pragma unroll
  for (int c = 0; c < 4; ++c) xa[c] = *(const b16x8*)(xp + 32 * c);
  xp += 262144;

  int dA = 0, dC0 = 0, dC1 = 0;
  float hv0 = 0.f, hv1 = 0.f;

  for (int tb = 0; tb < 128; tb += 4) {
    #pragma unroll
    for (int u = 0; u < 4; ++u) {
      const int t = tb + u;
      const u16* rbuf = hring[u];
      u16* wbuf = hring[(u + 1) & 3];

      // fused head for pair (t-2, t-1), rotated across waves (reads slots (u+3)&3 and u)
      if (((t & 1) == 0) && (t >= 2) && (w == (((t - 2) >> 1) & 7))) {
        const u16* bufA = hring[(u + 3) & 3];   // h_{t-2}
        const char* hbase = (const char*)((col < 8) ? bufA : rbuf);
        f32x4 hacc = fzero4();
        #pragma unroll
        for (int c = 0; c < 4; ++c) {
          b16x8 hh = *(const b16x8*)(hbase + offr[c]);
          b16x8 wf = *(const b16x8*)(Whb + col * 128 + 8 * q + 32 * c);
          hacc = MFMA16(hh, wf, hacc);
        }
        #pragma unroll
        for (int r = 0; r < 4; ++r) {
          int m = 4 * q + r;
          int tt = (t - 2) + (m >> 3);
          int n = n0 + (m & 3);              // mirror rows double-write same value
          float v = hacc[r] + hb;
          if (col < 6)       out[(tt * 2048 + n) * 6 + col] = v;
          else if (col == 6) out[1572864 + tt * 2048 + n] = v;
        }
      }

      // h_{t-1} fragments; zero rows where episode ended at t-1
      b16x8 ha[4];
      #pragma unroll
      for (int c = 0; c < 4; ++c) {
        ha[c] = *(const b16x8*)((const char*)rbuf + offr[c]);
        if (dA) ha[c] = bzero8();
      }
      if (dC0) cc0 = 0.f;
      if (dC1) cc1 = 0.f;

      // prefetch next step's x fragments (flies across barriers; no vmcnt drain)
      b16x8 xn[4];
      #pragma unroll
      for (int c = 0; c < 4; ++c) xn[c] = *(const b16x8*)(xp + 32 * c);

      f32x4 acc[4];
      #pragma unroll
      for (int g = 0; g < 4; ++g) acc[g] = fzero4();
      #pragma unroll
      for (int g = 0; g < 4; ++g)
        #pragma unroll
        for (int c = 0; c < 4; ++c)
          acc[g] = MFMA16(xa[c], wih[g][c], acc[g]);
      #pragma unroll
      for (int g = 0; g < 4; ++g)
        #pragma unroll
        for (int c = 0; c < 4; ++c)
          acc[g] = MFMA16(ha[c], whh[g][c], acc[g]);

      // masks for next step (done[t]), mirrored rows
      dA  = dsh[t * 8 + cl];
      dC0 = dsh[t * 8 + rbase];
      dC1 = dsh[t * 8 + rbase + 1];

      // spread cells across all lanes: q2/q3 take partner's acc rows 2,3
      #pragma unroll
      for (int g = 0; g < 4; ++g) {
        asm volatile("v_permlane32_swap_b32 %0, %1" : "+v"(acc[g][0]), "+v"(acc[g][2]));
        asm volatile("v_permlane32_swap_b32 %0, %1" : "+v"(acc[g][1]), "+v"(acc[g][3]));
      }

      // elementwise LSTM cell, 2 cells/lane (gates pre-scaled by log2e)
      {
        float gi = acc[0][0] + gbr[0], gf = acc[1][0] + gbr[1];
        float gg = acc[2][0] + gbr[2], go = acc[3][0] + gbr[3];
        float si = rcp_f(1.f + exp2_f(-gi));
        float sf = rcp_f(1.f + exp2_f(-gf));
        float tg = 1.f - 2.f * rcp_f(1.f + exp2_f(gg + gg));
        float cn = sf * cc0 + si * tg;
        float so = rcp_f(1.f + exp2_f(-go));
        float tc = 1.f - 2.f * rcp_f(1.f + exp2_f(2.8853900817779268f * cn));
        cc0 = cn; hv0 = so * tc;
      }
      {
        float gi = acc[0][1] + gbr[0], gf = acc[1][1] + gbr[1];
        float gg = acc[2][1] + gbr[2], go = acc[3][1] + gbr[3];
        float si = rcp_f(1.f + exp2_f(-gi));
        float sf = rcp_f(1.f + exp2_f(-gf));
        float tg = 1.f - 2.f * rcp_f(1.f + exp2_f(gg + gg));
        float cn = sf * cc1 + si * tg;
        float so = rcp_f(1.f + exp2_f(-go));
        float tc = 1.f - 2.f * rcp_f(1.f + exp2_f(2.8853900817779268f * cn));
        cc1 = cn; hv1 = so * tc;
      }

      // pack h -> bf16, write to ring slot (u+1)&3 (mirror lanes write mirror rows)
      {
        u32 pk;
        asm("v_cvt_pk_bf16_f32 %0, %1, %2" : "=v"(pk) : "v"(hv0), "v"(hv1));
        *(u16*)((char*)wbuf + offw0) = (u16)pk;
        *(u16*)((char*)wbuf + offw1) = (u16)(pk >> 16);
      }
      bar_lgkm();   // LDS-only drain; global loads/stores stay in flight

      #pragma unroll
      for (int c = 0; c < 4; ++c) xa[c] = xn[c];
      xp += 262144;
    }
  }

  // final head pair (126,127): h126 in slot 3, h127 in slot 0
  if (w == 7) {
    const char* hbase = (const char*)((col < 8) ? hring[3] : hring[0]);
    f32x4 hacc = fzero4();
    #pragma unroll
    for (int c = 0; c < 4; ++c) {
      b16x8 hh = *(const b16x8*)(hbase + offr[c]);
      b16x8 wf = *(const b16x8*)(Whb + col * 128 + 8 * q + 32 * c);
      hacc = MFMA16(hh, wf, hacc);
    }
    #pragma unroll
    for (int r = 0; r < 4; ++r) {
      int m = 4 * q + r;
      int tt = 126 + (m >> 3);
      int n = n0 + (m & 3);
      float v = hacc[r] + hb;
      if (col < 6)       out[(tt * 2048 + n) * 6 + col] = v;
      else if (col == 6) out[1572864 + tt * 2048 + n] = v;
    }
  }

  // final hT / cT (f32), 2 rows per lane — only non-mirror lanes (rbase 0,2)
  if (!(rbase & 4)) {
    int k = 16 * w + col;
    out[1835008 + (n0 + rbase) * 128 + k]     = hv0;
    out[1835008 + (n0 + rbase + 1) * 128 + k] = hv1;
    out[2097152 + (n0 + rbase) * 128 + k]     = cc0;
    out[2097152 + (n0 + rbase + 1) * 128 + k] = cc1;
  }
}

extern "C" void kernel_launch(void* const* d_in, const int* in_sizes, int n_in,
                              void* d_out, int out_size, void* d_ws, size_t ws_size,
                              hipStream_t stream) {
  const float* obs  = (const float*)d_in[0];
  const float* h0   = (const float*)d_in[1];
  const float* c0   = (const float*)d_in[2];
  const int*   done = (const int*)d_in[3];
  const float* W1   = (const float*)d_in[4];
  const float* b1   = (const float*)d_in[5];
  const float* W2   = (const float*)d_in[6];
  const float* b2   = (const float*)d_in[7];
  const float* Wih  = (const float*)d_in[8];
  const float* Whh  = (const float*)d_in[9];
  const float* bih  = (const float*)d_in[10];
  const float* bhh  = (const float*)d_in[11];
  const float* Wp   = (const float*)d_in[12];
  const float* bp   = (const float*)d_in[13];
  const float* Wv   = (const float*)d_in[14];
  const float* bv   = (const float*)d_in[15];

  char* ws = (char*)d_ws;
  u16*   X2   = (u16*)(ws);                                      // 67108864 B
  u16*   W1b  = (u16*)(ws + 67108864);                           // 16384 B
  u16*   W2b  = (u16*)(ws + 67108864 + 16384);                   // 32768 B
  u16*   Wihb = (u16*)(ws + 67108864 + 16384 + 32768);           // 131072 B
  u16*   Whhb = (u16*)(ws + 67108864 + 16384 + 32768 + 131072);  // 131072 B
  u16*   Whb  = (u16*)(ws + 67108864 + 16384 + 32768 + 262144);  // 4096 B
  float* gbp  = (float*)(ws + 67108864 + 16384 + 32768 + 262144 + 4096);
  float* out  = (float*)d_out;

  hipLaunchKernelGGL(prep_kernel, dim3(256), dim3(256), 0, stream,
                     W1, W2, Wih, Whh, Wp, Wv, bih, bhh, W1b, W2b, Wihb, Whhb, Whb, gbp);
  hipLaunchKernelGGL(mlp_kernel, dim3(4096), dim3(256), 0, stream,
                     obs, b1, b2, W1b, W2b, X2);
  hipLaunchKernelGGL(lstm_kernel, dim3(512), dim3(512), 0, stream,
                     X2, h0, c0, done, Wihb, Whhb, Whb, gbp, bp, bv, out);
}

// Round 7
// 265.040 us; speedup vs baseline: 7.5490x; 1.8056x over previous
//
#include <hip/hip_runtime.h>

typedef __attribute__((ext_vector_type(8))) __bf16 b16x8;
typedef __attribute__((ext_vector_type(4))) float f32x4;
typedef unsigned short u16;
typedef unsigned int u32;

#define MFMA16(a, b, c) __builtin_amdgcn_mfma_f32_16x16x32_bf16((a), (b), (c), 0, 0, 0)
// XOR swizzle: spread 16B slots across banks for row-major bf16 tiles w/ 256B row stride
#define SW(byteoff, row) ((byteoff) ^ (((row) & 7) << 4))
#define LOG2E 1.4426950408889634f

__device__ __forceinline__ u16 f2bf_bits(float f) {
  union { float f; unsigned u; } v; v.f = f;
  unsigned r = (v.u + 0x7FFFu + ((v.u >> 16) & 1u)) >> 16;
  return (u16)r;
}
__device__ __forceinline__ float rcp_f(float x) { float r; asm("v_rcp_f32 %0, %1" : "=v"(r) : "v"(x)); return r; }
__device__ __forceinline__ float exp2_f(float x) { float r; asm("v_exp_f32 %0, %1" : "=v"(r) : "v"(x)); return r; }
__device__ __forceinline__ f32x4 fzero4() { f32x4 z; z[0]=0.f; z[1]=0.f; z[2]=0.f; z[3]=0.f; return z; }
__device__ __forceinline__ b16x8 bzero8() {
  b16x8 z;
  #pragma unroll
  for (int j = 0; j < 8; ++j) z[j] = (__bf16)0.f;
  return z;
}
// barrier that drains only LDS (no vmcnt drain): loads/stores fly across
__device__ __forceinline__ void bar_lgkm() {
  asm volatile("s_waitcnt lgkmcnt(0)\n\ts_barrier" ::: "memory");
}

// ---------------- prep: weights -> bf16 (gate weights pre-scaled by log2e) ----------------
__global__ __launch_bounds__(256) void prep_kernel(
    const float* __restrict__ W1, const float* __restrict__ W2,
    const float* __restrict__ Wih, const float* __restrict__ Whh,
    const float* __restrict__ Wp, const float* __restrict__ Wv,
    const float* __restrict__ bih, const float* __restrict__ bhh,
    u16* __restrict__ W1b, u16* __restrict__ W2b, u16* __restrict__ Wihb,
    u16* __restrict__ Whhb, u16* __restrict__ Whb, float* __restrict__ gbp)
{
  int i = blockIdx.x * 256 + threadIdx.x;   // grid 256*256 = 65536
  if (i < 8192) {                            // W1 padded (128 x 64), K 54->64
    int r = i >> 6, k = i & 63;
    W1b[i] = f2bf_bits(k < 54 ? W1[r * 54 + k] : 0.f);
  }
  if (i < 16384) W2b[i] = f2bf_bits(W2[i]);  // 128x128
  Wihb[i] = f2bf_bits(LOG2E * Wih[i]);       // 512x128, pre-scaled
  Whhb[i] = f2bf_bits(LOG2E * Whh[i]);       // 512x128, pre-scaled
  if (i < 2048) {                            // head: rows 0-5 Wp, 6 Wv, 7-15 zero (16x128)
    int r = i >> 7, k = i & 127;
    float v = (r < 6) ? Wp[r * 128 + k] : ((r == 6) ? Wv[k] : 0.f);
    Whb[i] = f2bf_bits(v);                   // NOT scaled
  }
  if (i < 512) gbp[i] = LOG2E * (bih[i] + bhh[i]);
}

// ---------------- phase 1: X2 = relu(relu(obs@W1^T+b1)@W2^T+b2) as bf16 ----------------
__global__ __launch_bounds__(256) void mlp_kernel(
    const float* __restrict__ obs, const float* __restrict__ b1v, const float* __restrict__ b2v,
    const u16* __restrict__ W1b, const u16* __restrict__ W2b, u16* __restrict__ X2)
{
  __shared__ __align__(16) float obst[64 * 54];
  __shared__ u16 x1t[64 * 128];
  __shared__ u16 x2t[64 * 128];
  const int tid = threadIdx.x;
  const int w   = tid >> 6;
  const int l   = tid & 63;
  const int col = l & 15;
  const int q   = l >> 4;
  const long m0 = (long)blockIdx.x * 64;   // 4096 blocks * 64 rows = 262144 = T*N

  {
    const float* osrc = obs + m0 * 54;
    #pragma unroll
    for (int j = 0; j < 4; ++j) {
      int i4 = tid + 256 * j;
      if (i4 < 864) *(float4*)&obst[i4 * 4] = *(const float4*)&osrc[i4 * 4];
    }
  }
  __syncthreads();

  b16x8 a0[2];
  {
    const float* orow = obst + (16 * w + col) * 54;
    #pragma unroll
    for (int c = 0; c < 2; ++c) {
      #pragma unroll
      for (int p = 0; p < 4; ++p) {
        int k0 = 32 * c + 8 * q + 2 * p;
        float x0 = 0.f, x1 = 0.f;
        if (k0 < 54) { x0 = orow[k0]; x1 = orow[k0 + 1]; }
        a0[c][2 * p]     = (__bf16)x0;
        a0[c][2 * p + 1] = (__bf16)x1;
      }
    }
  }
  f32x4 acc[8];
  #pragma unroll
  for (int i = 0; i < 8; ++i) acc[i] = fzero4();
  #pragma unroll
  for (int nt = 0; nt < 8; ++nt) {
    #pragma unroll
    for (int c = 0; c < 2; ++c) {
      b16x8 b = *(const b16x8*)(W1b + (nt * 16 + col) * 64 + 8 * q + 32 * c);
      acc[nt] = MFMA16(a0[c], b, acc[nt]);
    }
  }
  #pragma unroll
  for (int nt = 0; nt < 8; ++nt) {
    float bb = b1v[nt * 16 + col];
    #pragma unroll
    for (int r = 0; r < 4; ++r) {
      float v = fmaxf(acc[nt][r] + bb, 0.f);
      int row = 16 * w + 4 * q + r;
      int byteoff = row * 256 + (nt * 16 + col) * 2;
      *(u16*)((char*)x1t + SW(byteoff, row)) = f2bf_bits(v);
    }
  }
  __syncthreads();

  b16x8 a1[4];
  #pragma unroll
  for (int c = 0; c < 4; ++c) {
    int row = 16 * w + col;
    int byteoff = row * 256 + 16 * q + 64 * c;
    a1[c] = *(const b16x8*)((char*)x1t + SW(byteoff, row));
  }
  f32x4 acc2[8];
  #pragma unroll
  for (int i = 0; i < 8; ++i) acc2[i] = fzero4();
  #pragma unroll
  for (int nt = 0; nt < 8; ++nt) {
    #pragma unroll
    for (int c = 0; c < 4; ++c) {
      b16x8 b = *(const b16x8*)(W2b + (nt * 16 + col) * 128 + 8 * q + 32 * c);
      acc2[nt] = MFMA16(a1[c], b, acc2[nt]);
    }
  }
  #pragma unroll
  for (int nt = 0; nt < 8; ++nt) {
    float bb = b2v[nt * 16 + col];
    #pragma unroll
    for (int r = 0; r < 4; ++r) {
      float v = fmaxf(acc2[nt][r] + bb, 0.f);
      int row = 16 * w + 4 * q + r;
      int byteoff = row * 256 + (nt * 16 + col) * 2;
      *(u16*)((char*)x2t + SW(byteoff, row)) = f2bf_bits(v);
    }
  }
  __syncthreads();

  #pragma unroll
  for (int i = 0; i < 4; ++i) {
    int e = tid + 256 * i;
    int byteoff = e * 16;
    int row = byteoff >> 8;
    uint4 v = *(const uint4*)((char*)x2t + SW(byteoff, row));
    *(uint4*)((char*)X2 + m0 * 256 + byteoff) = v;
  }
}

// ---------------- phase 2: LSTM recurrence (uniform loop, h -> H buffer) ----------------
// 256 blocks x 8 batch rows, 512 threads (8 waves); wave w owns gate cols [16w,16w+16).
// No in-loop heads: h_t stored to dedicated H (never read in-kernel -> no vmcnt
// drain needed; bar_lgkm only waits LDS). Heads computed by head_kernel after.
__global__ __launch_bounds__(512) void lstm_kernel(
    const u16* __restrict__ X2, const float* __restrict__ h0, const float* __restrict__ c0,
    const int* __restrict__ done,
    const u16* __restrict__ Wihb, const u16* __restrict__ Whhb,
    const float* __restrict__ gb, u16* __restrict__ H, float* __restrict__ out)
{
  __shared__ u16 hring[4][8 * 128];  // 4-deep ring of h tiles (swizzled)
  __shared__ int dsh[1024];          // done[t][0..7] staged
  const int tid = threadIdx.x;
  const int w   = tid >> 6;
  const int l   = tid & 63;
  const int col = l & 15;
  const int q   = l >> 4;
  const int cl  = col & 7;
  const int n0  = blockIdx.x * 8;    // 256 blocks * 8 rows = 2048
  // elementwise-spread row base: q0->0, q1->4, q2->2, q3->6 (each lane owns rows rbase, rbase+1)
  const int rbase = ((q & 1) << 2) + ((q >> 1) << 1);

  // resident gate-weight fragments (pre-scaled by log2e)
  b16x8 wih[4][4], whh[4][4];
  #pragma unroll
  for (int g = 0; g < 4; ++g) {
    int nt = 8 * g + w;
    #pragma unroll
    for (int c = 0; c < 4; ++c) {
      wih[g][c] = *(const b16x8*)(Wihb + (nt * 16 + col) * 128 + 8 * q + 32 * c);
      whh[g][c] = *(const b16x8*)(Whhb + (nt * 16 + col) * 128 + 8 * q + 32 * c);
    }
  }
  float gbr[4];
  #pragma unroll
  for (int g = 0; g < 4; ++g) gbr[g] = gb[(8 * g + w) * 16 + col];

  // c-state: 2 cells per lane (rows rbase, rbase+1; hcol 16w+col)
  float cc0 = c0[(n0 + rbase) * 128 + 16 * w + col];
  float cc1 = c0[(n0 + rbase + 1) * 128 + 16 * w + col];

  // stage h0 -> hring[0]; done -> dsh
  #pragma unroll
  for (int j = 0; j < 2; ++j) {
    int idx = tid * 2 + j;           // 1024 = 8 rows * 128
    int row = idx >> 7, k = idx & 127;
    *(u16*)((char*)hring[0] + SW(row * 256 + k * 2, row)) = f2bf_bits(h0[(n0 + row) * 128 + k]);
    dsh[idx] = done[(idx >> 3) * 2048 + n0 + (idx & 7)];
  }
  __syncthreads();

  // loop-invariant LDS offsets
  int offr[4];
  #pragma unroll
  for (int c = 0; c < 4; ++c) offr[c] = SW(cl * 256 + 16 * q + 64 * c, cl);
  const int wcol2 = (16 * w + col) * 2;
  const int offw0 = SW(rbase * 256 + wcol2, rbase);
  const int offw1 = SW((rbase + 1) * 256 + wcol2, rbase + 1);

  // H store pointers (u16; rows rbase, rbase+1; col 16w+col), advanced by 2048*128/step
  u16* hp0 = H + (long)(n0 + rbase) * 128 + 16 * w + col;
  u16* hp1 = H + (long)(n0 + rbase + 1) * 128 + 16 * w + col;

  // x2 fragment pointer (per-lane); t=0 preloaded, xp then points at t+1
  const u16* xp = X2 + (n0 + cl) * 128 + 8 * q;
  b16x8 xa[4];
  #pragma unroll
  for (int c = 0; c < 4; ++c) xa[c] = *(const b16x8*)(xp + 32 * c);
  xp += 262144;

  int dA = 0, dC0 = 0, dC1 = 0;
  float hv0 = 0.f, hv1 = 0.f;

  for (int tb = 0; tb < 128; tb += 4) {
    #pragma unroll
    for (int u = 0; u < 4; ++u) {
      const int t = tb + u;
      const u16* rbuf = hring[u];
      u16* wbuf = hring[(u + 1) & 3];

      // h_{t-1} fragments; zero rows where episode ended at t-1
      b16x8 ha[4];
      #pragma unroll
      for (int c = 0; c < 4; ++c) {
        ha[c] = *(const b16x8*)((const char*)rbuf + offr[c]);
        if (dA) ha[c] = bzero8();
      }
      if (dC0) cc0 = 0.f;
      if (dC1) cc1 = 0.f;

      // prefetch next step's x fragments (flies across barriers; no vmcnt drain)
      b16x8 xn[4];
      #pragma unroll
      for (int c = 0; c < 4; ++c) xn[c] = *(const b16x8*)(xp + 32 * c);

      f32x4 acc[4];
      #pragma unroll
      for (int g = 0; g < 4; ++g) acc[g] = fzero4();
      __builtin_amdgcn_s_setprio(1);
      #pragma unroll
      for (int g = 0; g < 4; ++g)
        #pragma unroll
        for (int c = 0; c < 4; ++c)
          acc[g] = MFMA16(xa[c], wih[g][c], acc[g]);
      #pragma unroll
      for (int g = 0; g < 4; ++g)
        #pragma unroll
        for (int c = 0; c < 4; ++c)
          acc[g] = MFMA16(ha[c], whh[g][c], acc[g]);
      __builtin_amdgcn_s_setprio(0);

      // masks for next step (done[t])
      dA  = dsh[t * 8 + cl];
      dC0 = dsh[t * 8 + rbase];
      dC1 = dsh[t * 8 + rbase + 1];

      // spread cells across all lanes: q2/q3 take partner's acc rows 2,3
      #pragma unroll
      for (int g = 0; g < 4; ++g) {
        asm volatile("v_permlane32_swap_b32 %0, %1" : "+v"(acc[g][0]), "+v"(acc[g][2]));
        asm volatile("v_permlane32_swap_b32 %0, %1" : "+v"(acc[g][1]), "+v"(acc[g][3]));
      }

      // elementwise LSTM cell, 2 cells/lane (gates pre-scaled by log2e)
      {
        float gi = acc[0][0] + gbr[0], gf = acc[1][0] + gbr[1];
        float gg = acc[2][0] + gbr[2], go = acc[3][0] + gbr[3];
        float si = rcp_f(1.f + exp2_f(-gi));
        float sf = rcp_f(1.f + exp2_f(-gf));
        float tg = 1.f - 2.f * rcp_f(1.f + exp2_f(gg + gg));
        float cn = sf * cc0 + si * tg;
        float so = rcp_f(1.f + exp2_f(-go));
        float tc = 1.f - 2.f * rcp_f(1.f + exp2_f(2.8853900817779268f * cn));
        cc0 = cn; hv0 = so * tc;
      }
      {
        float gi = acc[0][1] + gbr[0], gf = acc[1][1] + gbr[1];
        float gg = acc[2][1] + gbr[2], go = acc[3][1] + gbr[3];
        float si = rcp_f(1.f + exp2_f(-gi));
        float sf = rcp_f(1.f + exp2_f(-gf));
        float tg = 1.f - 2.f * rcp_f(1.f + exp2_f(gg + gg));
        float cn = sf * cc1 + si * tg;
        float so = rcp_f(1.f + exp2_f(-go));
        float tc = 1.f - 2.f * rcp_f(1.f + exp2_f(2.8853900817779268f * cn));
        cc1 = cn; hv1 = so * tc;
      }

      // pack h -> bf16: LDS ring write + global H write (fire-and-forget)
      {
        u32 pk;
        asm("v_cvt_pk_bf16_f32 %0, %1, %2" : "=v"(pk) : "v"(hv0), "v"(hv1));
        *(u16*)((char*)wbuf + offw0) = (u16)pk;
        *(u16*)((char*)wbuf + offw1) = (u16)(pk >> 16);
        *hp0 = (u16)pk;
        *hp1 = (u16)(pk >> 16);
        hp0 += 262144; hp1 += 262144;
      }
      bar_lgkm();   // LDS-only drain; global loads/stores stay in flight

      #pragma unroll
      for (int c = 0; c < 4; ++c) xa[c] = xn[c];
      xp += 262144;
    }
  }

  // final hT / cT (f32), 2 rows per lane
  {
    int k = 16 * w + col;
    out[1835008 + (n0 + rbase) * 128 + k]     = hv0;
    out[1835008 + (n0 + rbase + 1) * 128 + k] = hv1;
    out[2097152 + (n0 + rbase) * 128 + k]     = cc0;
    out[2097152 + (n0 + rbase + 1) * 128 + k] = cc1;
  }
}

// ---------------- phase 3: heads (logits + value) from H, fully parallel ----------------
__global__ __launch_bounds__(256) void head_kernel(
    const u16* __restrict__ H, const u16* __restrict__ Whb,
    const float* __restrict__ bp, const float* __restrict__ bv, float* __restrict__ out)
{
  const int tid = threadIdx.x;
  const int w   = tid >> 6;
  const int l   = tid & 63;
  const int col = l & 15;
  const int q   = l >> 4;
  const long m0 = (long)blockIdx.x * 64;   // 4096 blocks * 64 rows

  b16x8 a[4], b[4];
  #pragma unroll
  for (int c = 0; c < 4; ++c) {
    a[c] = *(const b16x8*)(H + (m0 + 16 * w + col) * 128 + 8 * q + 32 * c);
    b[c] = *(const b16x8*)(Whb + col * 128 + 8 * q + 32 * c);
  }
  f32x4 acc = fzero4();
  #pragma unroll
  for (int c = 0; c < 4; ++c) acc = MFMA16(a[c], b[c], acc);
  float hb = (col < 6) ? bp[col] : ((col == 6) ? bv[0] : 0.f);
  #pragma unroll
  for (int r = 0; r < 4; ++r) {
    long m = m0 + 16 * w + 4 * q + r;    // global row index = t*2048+n
    float v = acc[r] + hb;
    if (col < 6)       out[m * 6 + col] = v;
    else if (col == 6) out[1572864 + m] = v;
  }
}

extern "C" void kernel_launch(void* const* d_in, const int* in_sizes, int n_in,
                              void* d_out, int out_size, void* d_ws, size_t ws_size,
                              hipStream_t stream) {
  const float* obs  = (const float*)d_in[0];
  const float* h0   = (const float*)d_in[1];
  const float* c0   = (const float*)d_in[2];
  const int*   done = (const int*)d_in[3];
  const float* W1   = (const float*)d_in[4];
  const float* b1   = (const float*)d_in[5];
  const float* W2   = (const float*)d_in[6];
  const float* b2   = (const float*)d_in[7];
  const float* Wih  = (const float*)d_in[8];
  const float* Whh  = (const float*)d_in[9];
  const float* bih  = (const float*)d_in[10];
  const float* bhh  = (const float*)d_in[11];
  const float* Wp   = (const float*)d_in[12];
  const float* bp   = (const float*)d_in[13];
  const float* Wv   = (const float*)d_in[14];
  const float* bv   = (const float*)d_in[15];

  char* ws = (char*)d_ws;
  u16*   X2   = (u16*)(ws);                                       // 67108864 B
  u16*   H    = (u16*)(ws + 67108864);                            // 67108864 B
  u16*   W1b  = (u16*)(ws + 134217728);                           // 16384 B
  u16*   W2b  = (u16*)(ws + 134217728 + 16384);                   // 32768 B
  u16*   Wihb = (u16*)(ws + 134217728 + 16384 + 32768);           // 131072 B
  u16*   Whhb = (u16*)(ws + 134217728 + 16384 + 32768 + 131072);  // 131072 B
  u16*   Whb  = (u16*)(ws + 134217728 + 16384 + 32768 + 262144);  // 4096 B
  float* gbp  = (float*)(ws + 134217728 + 16384 + 32768 + 262144 + 4096);
  float* out  = (float*)d_out;

  hipLaunchKernelGGL(prep_kernel, dim3(256), dim3(256), 0, stream,
                     W1, W2, Wih, Whh, Wp, Wv, bih, bhh, W1b, W2b, Wihb, Whhb, Whb, gbp);
  hipLaunchKernelGGL(mlp_kernel, dim3(4096), dim3(256), 0, stream,
                     obs, b1, b2, W1b, W2b, X2);
  hipLaunchKernelGGL(lstm_kernel, dim3(256), dim3(512), 0, stream,
                     X2, h0, c0, done, Wihb, Whhb, gbp, H, out);
  hipLaunchKernelGGL(head_kernel, dim3(4096), dim3(256), 0, stream,
                     H, Whb, bp, bv, out);
}

// Round 8
// 255.490 us; speedup vs baseline: 7.8312x; 1.0374x over previous
//
#include <hip/hip_runtime.h>

typedef __attribute__((ext_vector_type(8))) __bf16 b16x8;
typedef __attribute__((ext_vector_type(4))) float f32x4;
typedef unsigned short u16;
typedef unsigned int u32;

#define MFMA16(a, b, c) __builtin_amdgcn_mfma_f32_16x16x32_bf16((a), (b), (c), 0, 0, 0)
// XOR swizzle: spread 16B slots across banks for row-major bf16 tiles w/ 256B row stride
#define SW(byteoff, row) ((byteoff) ^ (((row) & 7) << 4))
#define LOG2E 1.4426950408889634f

__device__ __forceinline__ u16 f2bf_bits(float f) {
  union { float f; unsigned u; } v; v.f = f;
  unsigned r = (v.u + 0x7FFFu + ((v.u >> 16) & 1u)) >> 16;
  return (u16)r;
}
__device__ __forceinline__ float rcp_f(float x) { float r; asm("v_rcp_f32 %0, %1" : "=v"(r) : "v"(x)); return r; }
__device__ __forceinline__ float exp2_f(float x) { float r; asm("v_exp_f32 %0, %1" : "=v"(r) : "v"(x)); return r; }
__device__ __forceinline__ f32x4 fzero4() { f32x4 z; z[0]=0.f; z[1]=0.f; z[2]=0.f; z[3]=0.f; return z; }
__device__ __forceinline__ b16x8 bzero8() {
  b16x8 z;
  #pragma unroll
  for (int j = 0; j < 8; ++j) z[j] = (__bf16)0.f;
  return z;
}
// barrier that drains only LDS (no vmcnt drain): loads/stores fly across
__device__ __forceinline__ void bar_lgkm() {
  asm volatile("s_waitcnt lgkmcnt(0)\n\ts_barrier" ::: "memory");
}
// LSTM cell elementwise; gate pre-activations (incl. bias) already scaled by log2e
__device__ __forceinline__ void cellf(float gi, float gf, float gg, float go,
                                      float& cc, float& hv) {
  float si = rcp_f(1.f + exp2_f(-gi));
  float sf = rcp_f(1.f + exp2_f(-gf));
  float tg = 1.f - 2.f * rcp_f(1.f + exp2_f(gg + gg));
  float cn = sf * cc + si * tg;
  float so = rcp_f(1.f + exp2_f(-go));
  float tc = 1.f - 2.f * rcp_f(1.f + exp2_f(2.8853900817779268f * cn));
  cc = cn; hv = so * tc;
}

// ---------------- prep: weights -> bf16 (gate weights pre-scaled by log2e) ----------------
__global__ __launch_bounds__(256) void prep_kernel(
    const float* __restrict__ W1, const float* __restrict__ W2,
    const float* __restrict__ Wih, const float* __restrict__ Whh,
    const float* __restrict__ Wp, const float* __restrict__ Wv,
    const float* __restrict__ bih, const float* __restrict__ bhh,
    u16* __restrict__ W1b, u16* __restrict__ W2b, u16* __restrict__ Wihb,
    u16* __restrict__ Whhb, u16* __restrict__ Whb, float* __restrict__ gbp)
{
  int i = blockIdx.x * 256 + threadIdx.x;   // grid 256*256 = 65536
  if (i < 8192) {                            // W1 padded (128 x 64), K 54->64
    int r = i >> 6, k = i & 63;
    W1b[i] = f2bf_bits(k < 54 ? W1[r * 54 + k] : 0.f);
  }
  if (i < 16384) W2b[i] = f2bf_bits(W2[i]);  // 128x128
  Wihb[i] = f2bf_bits(LOG2E * Wih[i]);       // 512x128, pre-scaled
  Whhb[i] = f2bf_bits(LOG2E * Whh[i]);       // 512x128, pre-scaled
  if (i < 2048) {                            // head: rows 0-5 Wp, 6 Wv, 7-15 zero (16x128)
    int r = i >> 7, k = i & 127;
    float v = (r < 6) ? Wp[r * 128 + k] : ((r == 6) ? Wv[k] : 0.f);
    Whb[i] = f2bf_bits(v);                   // NOT scaled
  }
  if (i < 512) gbp[i] = LOG2E * (bih[i] + bhh[i]);
}

// ---------------- phase 1: X2 = relu(relu(obs@W1^T+b1)@W2^T+b2) as bf16 ----------------
__global__ __launch_bounds__(256) void mlp_kernel(
    const float* __restrict__ obs, const float* __restrict__ b1v, const float* __restrict__ b2v,
    const u16* __restrict__ W1b, const u16* __restrict__ W2b, u16* __restrict__ X2)
{
  __shared__ __align__(16) float obst[64 * 54];
  __shared__ u16 x1t[64 * 128];
  __shared__ u16 x2t[64 * 128];
  const int tid = threadIdx.x;
  const int w   = tid >> 6;
  const int l   = tid & 63;
  const int col = l & 15;
  const int q   = l >> 4;
  const long m0 = (long)blockIdx.x * 64;   // 4096 blocks * 64 rows = 262144 = T*N

  {
    const float* osrc = obs + m0 * 54;
    #pragma unroll
    for (int j = 0; j < 4; ++j) {
      int i4 = tid + 256 * j;
      if (i4 < 864) *(float4*)&obst[i4 * 4] = *(const float4*)&osrc[i4 * 4];
    }
  }
  __syncthreads();

  b16x8 a0[2];
  {
    const float* orow = obst + (16 * w + col) * 54;
    #pragma unroll
    for (int c = 0; c < 2; ++c) {
      #pragma unroll
      for (int p = 0; p < 4; ++p) {
        int k0 = 32 * c + 8 * q + 2 * p;
        float x0 = 0.f, x1 = 0.f;
        if (k0 < 54) { x0 = orow[k0]; x1 = orow[k0 + 1]; }
        a0[c][2 * p]     = (__bf16)x0;
        a0[c][2 * p + 1] = (__bf16)x1;
      }
    }
  }
  f32x4 acc[8];
  #pragma unroll
  for (int i = 0; i < 8; ++i) acc[i] = fzero4();
  #pragma unroll
  for (int nt = 0; nt < 8; ++nt) {
    #pragma unroll
    for (int c = 0; c < 2; ++c) {
      b16x8 b = *(const b16x8*)(W1b + (nt * 16 + col) * 64 + 8 * q + 32 * c);
      acc[nt] = MFMA16(a0[c], b, acc[nt]);
    }
  }
  #pragma unroll
  for (int nt = 0; nt < 8; ++nt) {
    float bb = b1v[nt * 16 + col];
    #pragma unroll
    for (int r = 0; r < 4; ++r) {
      float v = fmaxf(acc[nt][r] + bb, 0.f);
      int row = 16 * w + 4 * q + r;
      int byteoff = row * 256 + (nt * 16 + col) * 2;
      *(u16*)((char*)x1t + SW(byteoff, row)) = f2bf_bits(v);
    }
  }
  __syncthreads();

  b16x8 a1[4];
  #pragma unroll
  for (int c = 0; c < 4; ++c) {
    int row = 16 * w + col;
    int byteoff = row * 256 + 16 * q + 64 * c;
    a1[c] = *(const b16x8*)((char*)x1t + SW(byteoff, row));
  }
  f32x4 acc2[8];
  #pragma unroll
  for (int i = 0; i < 8; ++i) acc2[i] = fzero4();
  #pragma unroll
  for (int nt = 0; nt < 8; ++nt) {
    #pragma unroll
    for (int c = 0; c < 4; ++c) {
      b16x8 b = *(const b16x8*)(W2b + (nt * 16 + col) * 128 + 8 * q + 32 * c);
      acc2[nt] = MFMA16(a1[c], b, acc2[nt]);
    }
  }
  #pragma unroll
  for (int nt = 0; nt < 8; ++nt) {
    float bb = b2v[nt * 16 + col];
    #pragma unroll
    for (int r = 0; r < 4; ++r) {
      float v = fmaxf(acc2[nt][r] + bb, 0.f);
      int row = 16 * w + 4 * q + r;
      int byteoff = row * 256 + (nt * 16 + col) * 2;
      *(u16*)((char*)x2t + SW(byteoff, row)) = f2bf_bits(v);
    }
  }
  __syncthreads();

  #pragma unroll
  for (int i = 0; i < 4; ++i) {
    int e = tid + 256 * i;
    int byteoff = e * 16;
    int row = byteoff >> 8;
    uint4 v = *(const uint4*)((char*)x2t + SW(byteoff, row));
    *(uint4*)((char*)X2 + m0 * 256 + byteoff) = v;
  }
}

// ---------------- phase 2: LSTM recurrence + post-loop fused heads ----------------
// 256 blocks x 8 batch rows, 512 threads (8 waves); wave w owns gate cols [16w,16w+16).
// Software-pipelined: the 16 x@Wih MFMAs for step t+1 issue BEFORE the barrier of
// step t (independent of h_t) into a ping-pong accumulator pre-loaded with bias.
// x fragments double-buffered (xnA/xnB), loaded 1.5 steps ahead. h ring is 2-deep.
// h_t goes to LDS ring + global H; heads computed after the loop from L2-hot H.
__global__ __launch_bounds__(512) void lstm_kernel(
    const u16* __restrict__ X2, const float* __restrict__ h0, const float* __restrict__ c0,
    const int* __restrict__ done,
    const u16* __restrict__ Wihb, const u16* __restrict__ Whhb, const u16* __restrict__ Whb,
    const float* __restrict__ gb, const float* __restrict__ bp, const float* __restrict__ bv,
    u16* __restrict__ H, float* __restrict__ out)
{
  __shared__ u16 hbuf[2][8 * 128];   // 2-deep ping-pong h tile (swizzled)
  __shared__ int dsh[1024];          // done[t][0..7] staged
  const int tid = threadIdx.x;
  const int w   = tid >> 6;
  const int l   = tid & 63;
  const int col = l & 15;
  const int q   = l >> 4;
  const int cl  = col & 7;
  const int n0  = blockIdx.x * 8;    // 256 blocks * 8 rows = 2048
  // elementwise-spread row base: q0->0, q1->4, q2->2, q3->6 (each lane owns rows rbase, rbase+1)
  const int rbase = ((q & 1) << 2) + ((q >> 1) << 1);

  // resident gate-weight fragments (pre-scaled by log2e)
  b16x8 wih[4][4], whh[4][4];
  #pragma unroll
  for (int g = 0; g < 4; ++g) {
    int nt = 8 * g + w;
    #pragma unroll
    for (int c = 0; c < 4; ++c) {
      wih[g][c] = *(const b16x8*)(Wihb + (nt * 16 + col) * 128 + 8 * q + 32 * c);
      whh[g][c] = *(const b16x8*)(Whhb + (nt * 16 + col) * 128 + 8 * q + 32 * c);
    }
  }
  float gbr[4];
  #pragma unroll
  for (int g = 0; g < 4; ++g) gbr[g] = gb[(8 * g + w) * 16 + col];

  // c-state: 2 cells per lane (rows rbase, rbase+1; hcol 16w+col)
  float cc0 = c0[(n0 + rbase) * 128 + 16 * w + col];
  float cc1 = c0[(n0 + rbase + 1) * 128 + 16 * w + col];

  // stage h0 -> hbuf[0]; done -> dsh
  #pragma unroll
  for (int j = 0; j < 2; ++j) {
    int idx = tid * 2 + j;           // 1024 = 8 rows * 128
    int row = idx >> 7, k = idx & 127;
    *(u16*)((char*)hbuf[0] + SW(row * 256 + k * 2, row)) = f2bf_bits(h0[(n0 + row) * 128 + k]);
    dsh[idx] = done[(idx >> 3) * 2048 + n0 + (idx & 7)];
  }
  __syncthreads();

  // loop-invariant LDS offsets
  int offr[4];
  #pragma unroll
  for (int c = 0; c < 4; ++c) offr[c] = SW(cl * 256 + 16 * q + 64 * c, cl);
  const int wcol2 = (16 * w + col) * 2;
  const int offw0 = SW(rbase * 256 + wcol2, rbase);
  const int offw1 = SW((rbase + 1) * 256 + wcol2, rbase + 1);

  // H store pointers (u16; rows rbase, rbase+1; col 16w+col), advanced per step
  u16* hp0 = H + (long)(n0 + rbase) * 128 + 16 * w + col;
  u16* hp1 = H + (long)(n0 + rbase + 1) * 128 + 16 * w + col;

  const u16* xbase = X2 + (n0 + cl) * 128 + 8 * q;

  // double-buffered x fragments + ping-pong accumulators
  b16x8 xnA[4], xnB[4];
  #pragma unroll
  for (int c = 0; c < 4; ++c) xnA[c] = *(const b16x8*)(xbase + 32 * c);            // x(0)
  f32x4 accA[4], accB[4];
  #pragma unroll
  for (int g = 0; g < 4; ++g) { f32x4 z; z[0]=gbr[g]; z[1]=gbr[g]; z[2]=gbr[g]; z[3]=gbr[g]; accA[g] = z; }
  __builtin_amdgcn_s_setprio(1);
  #pragma unroll
  for (int g = 0; g < 4; ++g)
    #pragma unroll
    for (int c = 0; c < 4; ++c)
      accA[g] = MFMA16(xnA[c], wih[g][c], accA[g]);
  __builtin_amdgcn_s_setprio(0);
  #pragma unroll
  for (int c = 0; c < 4; ++c) xnB[c] = *(const b16x8*)(xbase + 262144 + 32 * c);   // x(1)

  int dA = 0, dC0 = 0, dC1 = 0;
  float hv0 = 0.f, hv1 = 0.f;

// one LSTM step. T_: timestep; RB/WB: h ring read/write; AC: acc holding bias+x(T_);
// AN: acc to pre-fill with bias+x(T_+1); XL: free x-buffer (reload with T_+2);
// XC: x-buffer holding x(T_+1), consumed by the pre-issued MFMAs at the tail.
#define LSTEP(T_, RB, WB, AC, AN, XL, XC) {                                          \
    b16x8 ha[4];                                                                     \
    _Pragma("unroll") for (int c = 0; c < 4; ++c) {                                  \
      ha[c] = *(const b16x8*)((const char*)(RB) + offr[c]);                          \
      if (dA) ha[c] = bzero8();                                                      \
    }                                                                                \
    if (dC0) cc0 = 0.f;                                                              \
    if (dC1) cc1 = 0.f;                                                              \
    { int t2 = (T_) + 2; if (t2 > 127) t2 = 127;                                     \
      const u16* xp2 = xbase + (long)t2 * 262144;                                    \
      _Pragma("unroll") for (int c = 0; c < 4; ++c)                                  \
        XL[c] = *(const b16x8*)(xp2 + 32 * c); }                                     \
    __builtin_amdgcn_s_setprio(1);                                                   \
    _Pragma("unroll") for (int g = 0; g < 4; ++g)                                    \
      _Pragma("unroll") for (int c = 0; c < 4; ++c)                                  \
        AC[g] = MFMA16(ha[c], whh[g][c], AC[g]);                                     \
    __builtin_amdgcn_s_setprio(0);                                                   \
    dA  = dsh[(T_) * 8 + cl];                                                        \
    dC0 = dsh[(T_) * 8 + rbase];                                                     \
    dC1 = dsh[(T_) * 8 + rbase + 1];                                                 \
    _Pragma("unroll") for (int g = 0; g < 4; ++g) {                                  \
      asm volatile("v_permlane32_swap_b32 %0, %1" : "+v"(AC[g][0]), "+v"(AC[g][2])); \
      asm volatile("v_permlane32_swap_b32 %0, %1" : "+v"(AC[g][1]), "+v"(AC[g][3])); \
    }                                                                                \
    cellf(AC[0][0], AC[1][0], AC[2][0], AC[3][0], cc0, hv0);                         \
    cellf(AC[0][1], AC[1][1], AC[2][1], AC[3][1], cc1, hv1);                         \
    { u32 pk;                                                                        \
      asm("v_cvt_pk_bf16_f32 %0, %1, %2" : "=v"(pk) : "v"(hv0), "v"(hv1));           \
      *(u16*)((char*)(WB) + offw0) = (u16)pk;                                        \
      *(u16*)((char*)(WB) + offw1) = (u16)(pk >> 16);                                \
      *hp0 = (u16)pk;                                                                \
      *hp1 = (u16)(pk >> 16);                                                        \
      hp0 += 262144; hp1 += 262144; }                                                \
    _Pragma("unroll") for (int g = 0; g < 4; ++g) {                                  \
      f32x4 z; z[0]=gbr[g]; z[1]=gbr[g]; z[2]=gbr[g]; z[3]=gbr[g]; AN[g] = z; }      \
    __builtin_amdgcn_s_setprio(1);                                                   \
    _Pragma("unroll") for (int g = 0; g < 4; ++g)                                    \
      _Pragma("unroll") for (int c = 0; c < 4; ++c)                                  \
        AN[g] = MFMA16(XC[c], wih[g][c], AN[g]);                                     \
    __builtin_amdgcn_s_setprio(0);                                                   \
    bar_lgkm();                                                                      \
  }

  for (int tb = 0; tb < 128; tb += 2) {
    LSTEP(tb,     hbuf[0], hbuf[1], accA, accB, xnA, xnB)
    LSTEP(tb + 1, hbuf[1], hbuf[0], accB, accA, xnB, xnA)
  }
#undef LSTEP

  // final hT / cT (f32), 2 rows per lane
  {
    int k = 16 * w + col;
    out[1835008 + (n0 + rbase) * 128 + k]     = hv0;
    out[1835008 + (n0 + rbase + 1) * 128 + k] = hv1;
    out[2097152 + (n0 + rbase) * 128 + k]     = cc0;
    out[2097152 + (n0 + rbase + 1) * 128 + k] = cc1;
  }

  // drain all H stores from every wave, then compute heads from own (L2-hot) H slice
  __syncthreads();
  {
    b16x8 wh[4];
    #pragma unroll
    for (int c = 0; c < 4; ++c) wh[c] = *(const b16x8*)(Whb + col * 128 + 8 * q + 32 * c);
    const float hb = (col < 6) ? bp[col] : ((col == 6) ? bv[0] : 0.f);
    // wave w handles t-pairs t0 = 16w + 2i, i = 0..7 (64 pairs total)
    #pragma unroll
    for (int i = 0; i < 8; ++i) {
      int t0 = 16 * w + 2 * i;
      // A-tile row = col: rows 0-7 -> (t0, n0+col), rows 8-15 -> (t0+1, n0+col-8)
      const u16* hsrc = H + ((long)(t0 + (col >> 3)) * 2048 + n0 + (col & 7)) * 128 + 8 * q;
      b16x8 a[4];
      #pragma unroll
      for (int c = 0; c < 4; ++c) a[c] = *(const b16x8*)(hsrc + 32 * c);
      f32x4 hacc = fzero4();
      #pragma unroll
      for (int c = 0; c < 4; ++c) hacc = MFMA16(a[c], wh[c], hacc);
      #pragma unroll
      for (int r = 0; r < 4; ++r) {
        int m = 4 * q + r;
        int tt = t0 + (m >> 3);
        int n = n0 + (m & 7);
        float v = hacc[r] + hb;
        if (col < 6)       out[(tt * 2048 + n) * 6 + col] = v;
        else if (col == 6) out[1572864 + tt * 2048 + n] = v;
      }
    }
  }
}

extern "C" void kernel_launch(void* const* d_in, const int* in_sizes, int n_in,
                              void* d_out, int out_size, void* d_ws, size_t ws_size,
                              hipStream_t stream) {
  const float* obs  = (const float*)d_in[0];
  const float* h0   = (const float*)d_in[1];
  const float* c0   = (const float*)d_in[2];
  const int*   done = (const int*)d_in[3];
  const float* W1   = (const float*)d_in[4];
  const float* b1   = (const float*)d_in[5];
  const float* W2   = (const float*)d_in[6];
  const float* b2   = (const float*)d_in[7];
  const float* Wih  = (const float*)d_in[8];
  const float* Whh  = (const float*)d_in[9];
  const float* bih  = (const float*)d_in[10];
  const float* bhh  = (const float*)d_in[11];
  const float* Wp   = (const float*)d_in[12];
  const float* bp   = (const float*)d_in[13];
  const float* Wv   = (const float*)d_in[14];
  const float* bv   = (const float*)d_in[15];

  char* ws = (char*)d_ws;
  u16*   X2   = (u16*)(ws);                                       // 67108864 B
  u16*   H    = (u16*)(ws + 67108864);                            // 67108864 B
  u16*   W1b  = (u16*)(ws + 134217728);                           // 16384 B
  u16*   W2b  = (u16*)(ws + 134217728 + 16384);                   // 32768 B
  u16*   Wihb = (u16*)(ws + 134217728 + 16384 + 32768);           // 131072 B
  u16*   Whhb = (u16*)(ws + 134217728 + 16384 + 32768 + 131072);  // 131072 B
  u16*   Whb  = (u16*)(ws + 134217728 + 16384 + 32768 + 262144);  // 4096 B
  float* gbp  = (float*)(ws + 134217728 + 16384 + 32768 + 262144 + 4096);
  float* out  = (float*)d_out;

  hipLaunchKernelGGL(prep_kernel, dim3(256), dim3(256), 0, stream,
                     W1, W2, Wih, Whh, Wp, Wv, bih, bhh, W1b, W2b, Wihb, Whhb, Whb, gbp);
  hipLaunchKernelGGL(mlp_kernel, dim3(4096), dim3(256), 0, stream,
                     obs, b1, b2, W1b, W2b, X2);
  hipLaunchKernelGGL(lstm_kernel, dim3(256), dim3(512), 0, stream,
                     X2, h0, c0, done, Wihb, Whhb, Whb, gbp, bp, bv, H, out);
}

// Round 9
// 242.336 us; speedup vs baseline: 8.2562x; 1.0543x over previous
//
#include <hip/hip_runtime.h>

typedef __attribute__((ext_vector_type(8))) __bf16 b16x8;
typedef __attribute__((ext_vector_type(4))) float f32x4;
typedef unsigned short u16;
typedef unsigned int u32;

#define MFMA16(a, b, c) __builtin_amdgcn_mfma_f32_16x16x32_bf16((a), (b), (c), 0, 0, 0)
// XOR swizzle: spread 16B slots across banks for row-major bf16 tiles w/ 256B row stride
#define SW(byteoff, row) ((byteoff) ^ (((row) & 7) << 4))
#define LOG2E 1.4426950408889634f

__device__ __forceinline__ u16 f2bf_bits(float f) {
  union { float f; unsigned u; } v; v.f = f;
  unsigned r = (v.u + 0x7FFFu + ((v.u >> 16) & 1u)) >> 16;
  return (u16)r;
}
__device__ __forceinline__ float rcp_f(float x) { float r; asm("v_rcp_f32 %0, %1" : "=v"(r) : "v"(x)); return r; }
__device__ __forceinline__ float exp2_f(float x) { float r; asm("v_exp_f32 %0, %1" : "=v"(r) : "v"(x)); return r; }
__device__ __forceinline__ f32x4 fzero4() { f32x4 z; z[0]=0.f; z[1]=0.f; z[2]=0.f; z[3]=0.f; return z; }
__device__ __forceinline__ b16x8 bzero8() {
  b16x8 z;
  #pragma unroll
  for (int j = 0; j < 8; ++j) z[j] = (__bf16)0.f;
  return z;
}
// barrier that drains only LDS (no vmcnt drain): loads/stores fly across
__device__ __forceinline__ void bar_lgkm() {
  asm volatile("s_waitcnt lgkmcnt(0)\n\ts_barrier" ::: "memory");
}
// LSTM cell elementwise; gate pre-activations (incl. bias) already scaled by log2e
__device__ __forceinline__ void cellf(float gi, float gf, float gg, float go,
                                      float& cc, float& hv) {
  float si = rcp_f(1.f + exp2_f(-gi));
  float sf = rcp_f(1.f + exp2_f(-gf));
  float tg = 1.f - 2.f * rcp_f(1.f + exp2_f(gg + gg));
  float cn = sf * cc + si * tg;
  float so = rcp_f(1.f + exp2_f(-go));
  float tc = 1.f - 2.f * rcp_f(1.f + exp2_f(2.8853900817779268f * cn));
  cc = cn; hv = so * tc;
}

// ---------------- prep: weights -> bf16 (gate weights pre-scaled by log2e) ----------------
__global__ __launch_bounds__(256) void prep_kernel(
    const float* __restrict__ W1, const float* __restrict__ W2,
    const float* __restrict__ Wih, const float* __restrict__ Whh,
    const float* __restrict__ Wp, const float* __restrict__ Wv,
    const float* __restrict__ bih, const float* __restrict__ bhh,
    u16* __restrict__ W1b, u16* __restrict__ W2b, u16* __restrict__ Wihb,
    u16* __restrict__ Whhb, u16* __restrict__ Whb, float* __restrict__ gbp)
{
  int i = blockIdx.x * 256 + threadIdx.x;   // grid 256*256 = 65536
  if (i < 8192) {                            // W1 padded (128 x 64), K 54->64
    int r = i >> 6, k = i & 63;
    W1b[i] = f2bf_bits(k < 54 ? W1[r * 54 + k] : 0.f);
  }
  if (i < 16384) W2b[i] = f2bf_bits(W2[i]);  // 128x128
  Wihb[i] = f2bf_bits(LOG2E * Wih[i]);       // 512x128, pre-scaled
  Whhb[i] = f2bf_bits(LOG2E * Whh[i]);       // 512x128, pre-scaled
  if (i < 2048) {                            // head: rows 0-5 Wp, 6 Wv, 7-15 zero (16x128)
    int r = i >> 7, k = i & 127;
    float v = (r < 6) ? Wp[r * 128 + k] : ((r == 6) ? Wv[k] : 0.f);
    Whb[i] = f2bf_bits(v);                   // NOT scaled
  }
  if (i < 512) gbp[i] = LOG2E * (bih[i] + bhh[i]);
}

// ---------------- fused MLP + LSTM recurrence + heads ----------------
// 256 blocks x 8 batch rows, 512 threads (8 waves); wave w owns gate cols [16w,16w+16)
// AND MLP N-tile nt=w. Per step t the block computes X1(t+3) and X2(t+2) into 2-deep
// swizzled LDS rings (x1tl/xtl); the recurrence consumes x from LDS. obs loaded as
// per-lane float2s (rows contiguous). x-MFMAs for t+1 pre-issued before the barrier.
// h_t -> LDS ring + global H (never read in-loop -> no vmcnt drain); heads after loop.
__global__ __launch_bounds__(512) void lstm_fused_kernel(
    const float* __restrict__ obs, const float* __restrict__ h0, const float* __restrict__ c0,
    const int* __restrict__ done,
    const u16* __restrict__ W1b, const u16* __restrict__ W2b,
    const u16* __restrict__ Wihb, const u16* __restrict__ Whhb, const u16* __restrict__ Whb,
    const float* __restrict__ gb, const float* __restrict__ b1v, const float* __restrict__ b2v,
    const float* __restrict__ bp, const float* __restrict__ bv,
    u16* __restrict__ H, float* __restrict__ out)
{
  __shared__ u16 hbuf[2][8 * 128];   // ping-pong h tiles (swizzled)
  __shared__ u16 x1tl[2][8 * 128];   // X1 ring (swizzled)
  __shared__ u16 xtl[2][8 * 128];    // X2 (gate-input x) ring (swizzled)
  __shared__ int dsh[1024];          // done[t][0..7] staged
  const int tid = threadIdx.x;
  const int w   = tid >> 6;
  const int l   = tid & 63;
  const int col = l & 15;
  const int q   = l >> 4;
  const int cl  = col & 7;
  const int n0  = blockIdx.x * 8;    // 256 blocks * 8 rows = 2048
  const int rbase = ((q & 1) << 2) + ((q >> 1) << 1);

  // resident gate-weight fragments (pre-scaled by log2e)
  b16x8 wih[4][4], whh[4][4];
  #pragma unroll
  for (int g = 0; g < 4; ++g) {
    int nt = 8 * g + w;
    #pragma unroll
    for (int c = 0; c < 4; ++c) {
      wih[g][c] = *(const b16x8*)(Wihb + (nt * 16 + col) * 128 + 8 * q + 32 * c);
      whh[g][c] = *(const b16x8*)(Whhb + (nt * 16 + col) * 128 + 8 * q + 32 * c);
    }
  }
  float gbr[4];
  #pragma unroll
  for (int g = 0; g < 4; ++g) gbr[g] = gb[(8 * g + w) * 16 + col];

  // resident MLP weight fragments for N-tile nt=w
  b16x8 w1f[2], w2f[4];
  #pragma unroll
  for (int c = 0; c < 2; ++c) w1f[c] = *(const b16x8*)(W1b + (w * 16 + col) * 64 + 8 * q + 32 * c);
  #pragma unroll
  for (int c = 0; c < 4; ++c) w2f[c] = *(const b16x8*)(W2b + (w * 16 + col) * 128 + 8 * q + 32 * c);
  const float b1r = b1v[w * 16 + col];
  const float b2r = b2v[w * 16 + col];

  // c-state
  float cc0 = c0[(n0 + rbase) * 128 + 16 * w + col];
  float cc1 = c0[(n0 + rbase + 1) * 128 + 16 * w + col];

  // stage h0 -> hbuf[0]; done -> dsh
  #pragma unroll
  for (int j = 0; j < 2; ++j) {
    int idx = tid * 2 + j;
    int row = idx >> 7, k = idx & 127;
    *(u16*)((char*)hbuf[0] + SW(row * 256 + k * 2, row)) = f2bf_bits(h0[(n0 + row) * 128 + k]);
    dsh[idx] = done[(idx >> 3) * 2048 + n0 + (idx & 7)];
  }

  // loop-invariant LDS offsets
  int offr[4];
  #pragma unroll
  for (int c = 0; c < 4; ++c) offr[c] = SW(cl * 256 + 16 * q + 64 * c, cl);
  const int wcol2 = (16 * w + col) * 2;
  const int offw0 = SW(rbase * 256 + wcol2, rbase);
  const int offw1 = SW((rbase + 1) * 256 + wcol2, rbase + 1);
  int swoff[4];                      // MLP output writes: rows m=4q+r (valid q<2), col 16w+col
  #pragma unroll
  for (int r = 0; r < 4; ++r) { int m = 4 * q + r; swoff[r] = SW(m * 256 + wcol2, m); }

  // obs addressing: lane reads row n0+cl, k = 32c+8q+2p (pairs; clamped+zeroed >=54)
  const long obl = (long)(n0 + cl) * 54;
  int koff[8]; bool kval[8];
  #pragma unroll
  for (int c = 0; c < 2; ++c)
    #pragma unroll
    for (int p = 0; p < 4; ++p) {
      int i = c * 4 + p, kk = 32 * c + 8 * q + 2 * p;
      kval[i] = (kk < 54); koff[i] = kval[i] ? kk : 0;
    }

  // H store pointers
  u16* hp0 = H + (long)(n0 + rbase) * 128 + 16 * w + col;
  u16* hp1 = H + (long)(n0 + rbase + 1) * 128 + 16 * w + col;

  // ---- MLP phase helpers ----
  auto MLPX1 = [&](int T, u16* dst) {
    const float* obsT = obs + (long)T * 110592 + obl;
    float2 o[8];
    #pragma unroll
    for (int i = 0; i < 8; ++i) o[i] = *(const float2*)(obsT + koff[i]);
    b16x8 a0[2];
    #pragma unroll
    for (int c = 0; c < 2; ++c)
      #pragma unroll
      for (int p = 0; p < 4; ++p) {
        int i = c * 4 + p;
        a0[c][2 * p]     = (__bf16)(kval[i] ? o[i].x : 0.f);
        a0[c][2 * p + 1] = (__bf16)(kval[i] ? o[i].y : 0.f);
      }
    f32x4 a = fzero4();
    a = MFMA16(a0[0], w1f[0], a);
    a = MFMA16(a0[1], w1f[1], a);
    if (q < 2) {
      #pragma unroll
      for (int r = 0; r < 4; ++r)
        *(u16*)((char*)dst + swoff[r]) = f2bf_bits(fmaxf(a[r] + b1r, 0.f));
    }
  };
  auto MLPX2 = [&](const u16* src, u16* dst) {
    b16x8 a1[4];
    #pragma unroll
    for (int c = 0; c < 4; ++c) a1[c] = *(const b16x8*)((const char*)src + offr[c]);
    f32x4 a = fzero4();
    #pragma unroll
    for (int c = 0; c < 4; ++c) a = MFMA16(a1[c], w2f[c], a);
    if (q < 2) {
      #pragma unroll
      for (int r = 0; r < 4; ++r)
        *(u16*)((char*)dst + swoff[r]) = f2bf_bits(fmaxf(a[r] + b2r, 0.f));
    }
  };

  // ---- prologue: X1(0,1,2), X2(0,1), accA = bias + x(0) ----
  __syncthreads();                         // h0/dsh staged
  MLPX1(0, x1tl[0]); MLPX1(1, x1tl[1]);
  __syncthreads();                         // x1 tiles visible
  MLPX2(x1tl[0], xtl[0]); MLPX2(x1tl[1], xtl[1]);
  __syncthreads();                         // x tiles visible
  MLPX1(2, x1tl[0]);
  f32x4 accA[4], accB[4];
  {
    b16x8 xa[4];
    #pragma unroll
    for (int c = 0; c < 4; ++c) xa[c] = *(const b16x8*)((const char*)xtl[0] + offr[c]);
    #pragma unroll
    for (int g = 0; g < 4; ++g) { f32x4 z; z[0]=gbr[g]; z[1]=gbr[g]; z[2]=gbr[g]; z[3]=gbr[g]; accA[g] = z; }
    #pragma unroll
    for (int g = 0; g < 4; ++g)
      #pragma unroll
      for (int c = 0; c < 4; ++c)
        accA[g] = MFMA16(xa[c], wih[g][c], accA[g]);
  }
  __syncthreads();                         // X1(2) visible; enter loop

  int dA = 0, dC0 = 0, dC1 = 0;
  float hv0 = 0.f, hv1 = 0.f;

// one fused step. Slots (by parity of T_): X1R=x1tl[T&1] (X1(T+2), read by X2 phase),
// X1W=x1tl[(T+1)&1] (X1(T+3) written), XTR=xtl[(T+1)&1] (x(T+1), pre-MFMA read),
// XTW=xtl[T&1] (x(T+2) written). AC holds bias+x(T_); AN pre-filled for T_+1.
#define LSTEP(T_, RB, WB, AC, AN, X1R, X1W, XTR, XTW) {                              \
    b16x8 ha[4];                                                                     \
    _Pragma("unroll") for (int c = 0; c < 4; ++c) {                                  \
      ha[c] = *(const b16x8*)((const char*)(RB) + offr[c]);                          \
      if (dA) ha[c] = bzero8();                                                      \
    }                                                                                \
    if (dC0) cc0 = 0.f;                                                              \
    if (dC1) cc1 = 0.f;                                                              \
    __builtin_amdgcn_s_setprio(1);                                                   \
    _Pragma("unroll") for (int g = 0; g < 4; ++g)                                    \
      _Pragma("unroll") for (int c = 0; c < 4; ++c)                                  \
        AC[g] = MFMA16(ha[c], whh[g][c], AC[g]);                                     \
    __builtin_amdgcn_s_setprio(0);                                                   \
    dA  = dsh[(T_) * 8 + cl];                                                        \
    dC0 = dsh[(T_) * 8 + rbase];                                                     \
    dC1 = dsh[(T_) * 8 + rbase + 1];                                                 \
    _Pragma("unroll") for (int g = 0; g < 4; ++g) {                                  \
      asm volatile("v_permlane32_swap_b32 %0, %1" : "+v"(AC[g][0]), "+v"(AC[g][2])); \
      asm volatile("v_permlane32_swap_b32 %0, %1" : "+v"(AC[g][1]), "+v"(AC[g][3])); \
    }                                                                                \
    cellf(AC[0][0], AC[1][0], AC[2][0], AC[3][0], cc0, hv0);                         \
    cellf(AC[0][1], AC[1][1], AC[2][1], AC[3][1], cc1, hv1);                         \
    { u32 pk;                                                                        \
      asm("v_cvt_pk_bf16_f32 %0, %1, %2" : "=v"(pk) : "v"(hv0), "v"(hv1));           \
      *(u16*)((char*)(WB) + offw0) = (u16)pk;                                        \
      *(u16*)((char*)(WB) + offw1) = (u16)(pk >> 16);                                \
      *hp0 = (u16)pk; *hp1 = (u16)(pk >> 16);                                        \
      hp0 += 262144; hp1 += 262144; }                                                \
    { int t3 = (T_) + 3; if (t3 > 127) t3 = 127;                                     \
      MLPX1(t3, X1W); }                                                              \
    MLPX2(X1R, XTW);                                                                 \
    { b16x8 xa[4];                                                                   \
      _Pragma("unroll") for (int c = 0; c < 4; ++c)                                  \
        xa[c] = *(const b16x8*)((const char*)(XTR) + offr[c]);                       \
      _Pragma("unroll") for (int g = 0; g < 4; ++g) {                                \
        f32x4 z; z[0]=gbr[g]; z[1]=gbr[g]; z[2]=gbr[g]; z[3]=gbr[g]; AN[g] = z; }    \
      __builtin_amdgcn_s_setprio(1);                                                 \
      _Pragma("unroll") for (int g = 0; g < 4; ++g)                                  \
        _Pragma("unroll") for (int c = 0; c < 4; ++c)                                \
          AN[g] = MFMA16(xa[c], wih[g][c], AN[g]);                                   \
      __builtin_amdgcn_s_setprio(0);                                                 \
    }                                                                                \
    bar_lgkm();                                                                      \
  }

  for (int tb = 0; tb < 128; tb += 2) {
    LSTEP(tb,     hbuf[0], hbuf[1], accA, accB, x1tl[0], x1tl[1], xtl[1], xtl[0])
    LSTEP(tb + 1, hbuf[1], hbuf[0], accB, accA, x1tl[1], x1tl[0], xtl[0], xtl[1])
  }
#undef LSTEP

  // final hT / cT (f32), 2 rows per lane
  {
    int k = 16 * w + col;
    out[1835008 + (n0 + rbase) * 128 + k]     = hv0;
    out[1835008 + (n0 + rbase + 1) * 128 + k] = hv1;
    out[2097152 + (n0 + rbase) * 128 + k]     = cc0;
    out[2097152 + (n0 + rbase + 1) * 128 + k] = cc1;
  }

  // drain all H stores from every wave, then compute heads from own (L2-hot) H slice
  __syncthreads();
  {
    b16x8 wh[4];
    #pragma unroll
    for (int c = 0; c < 4; ++c) wh[c] = *(const b16x8*)(Whb + col * 128 + 8 * q + 32 * c);
    const float hb = (col < 6) ? bp[col] : ((col == 6) ? bv[0] : 0.f);
    #pragma unroll
    for (int i = 0; i < 8; ++i) {
      int t0 = 16 * w + 2 * i;
      const u16* hsrc = H + ((long)(t0 + (col >> 3)) * 2048 + n0 + (col & 7)) * 128 + 8 * q;
      b16x8 a[4];
      #pragma unroll
      for (int c = 0; c < 4; ++c) a[c] = *(const b16x8*)(hsrc + 32 * c);
      f32x4 hacc = fzero4();
      #pragma unroll
      for (int c = 0; c < 4; ++c) hacc = MFMA16(a[c], wh[c], hacc);
      #pragma unroll
      for (int r = 0; r < 4; ++r) {
        int m = 4 * q + r;
        int tt = t0 + (m >> 3);
        int n = n0 + (m & 7);
        float v = hacc[r] + hb;
        if (col < 6)       out[(tt * 2048 + n) * 6 + col] = v;
        else if (col == 6) out[1572864 + tt * 2048 + n] = v;
      }
    }
  }
}

extern "C" void kernel_launch(void* const* d_in, const int* in_sizes, int n_in,
                              void* d_out, int out_size, void* d_ws, size_t ws_size,
                              hipStream_t stream) {
  const float* obs  = (const float*)d_in[0];
  const float* h0   = (const float*)d_in[1];
  const float* c0   = (const float*)d_in[2];
  const int*   done = (const int*)d_in[3];
  const float* W1   = (const float*)d_in[4];
  const float* b1   = (const float*)d_in[5];
  const float* W2   = (const float*)d_in[6];
  const float* b2   = (const float*)d_in[7];
  const float* Wih  = (const float*)d_in[8];
  const float* Whh  = (const float*)d_in[9];
  const float* bih  = (const float*)d_in[10];
  const float* bhh  = (const float*)d_in[11];
  const float* Wp   = (const float*)d_in[12];
  const float* bp   = (const float*)d_in[13];
  const float* Wv   = (const float*)d_in[14];
  const float* bv   = (const float*)d_in[15];

  char* ws = (char*)d_ws;
  u16*   H    = (u16*)(ws);                                      // 67108864 B
  u16*   W1b  = (u16*)(ws + 67108864);                           // 16384 B
  u16*   W2b  = (u16*)(ws + 67108864 + 16384);                   // 32768 B
  u16*   Wihb = (u16*)(ws + 67108864 + 16384 + 32768);           // 131072 B
  u16*   Whhb = (u16*)(ws + 67108864 + 16384 + 32768 + 131072);  // 131072 B
  u16*   Whb  = (u16*)(ws + 67108864 + 16384 + 32768 + 262144);  // 4096 B
  float* gbp  = (float*)(ws + 67108864 + 16384 + 32768 + 262144 + 4096);
  float* out  = (float*)d_out;

  hipLaunchKernelGGL(prep_kernel, dim3(256), dim3(256), 0, stream,
                     W1, W2, Wih, Whh, Wp, Wv, bih, bhh, W1b, W2b, Wihb, Whhb, Whb, gbp);
  hipLaunchKernelGGL(lstm_fused_kernel, dim3(256), dim3(512), 0, stream,
                     obs, h0, c0, done, W1b, W2b, Wihb, Whhb, Whb, gbp, b1, b2, bp, bv, H, out);
}